// Round 3
// baseline (1986.106 us; speedup 1.0000x reference)
//
#include <hip/hip_runtime.h>
#include <hip/hip_bf16.h>
#include <stdint.h>
#include <type_traits>

typedef __hip_bfloat16 hbf16;
typedef short bf16x8 __attribute__((ext_vector_type(8)));
typedef float f32x4 __attribute__((ext_vector_type(4)));

#define MFMA16(a, b, c) __builtin_amdgcn_mfma_f32_16x16x32_bf16((a), (b), (c), 0, 0, 0)

__device__ __forceinline__ void gload_lds16(const void* g, void* l) {
  __builtin_amdgcn_global_load_lds(
      (const __attribute__((address_space(1))) void*)g,
      (__attribute__((address_space(3))) void*)l, 16, 0, 0);
}

__device__ __forceinline__ float b2f(unsigned short u) {
  union { unsigned int u32; float f; } cv;
  cv.u32 = ((unsigned int)u) << 16;
  return cv.f;
}
__device__ __forceinline__ unsigned short f2b(float f) {
  hbf16 h = __float2bfloat16(f);
  return __builtin_bit_cast(unsigned short, h);
}

// element-index XOR swizzle for 64-col bf16 LDS tiles (attn kernels)
__device__ __forceinline__ int swz(int row, int col) {
  return row * 64 + (col ^ ((row & 7) << 3));
}

// ---------------------------------------------------------------------------
// fp32 -> bf16 conversion. n must be a multiple of 8.
// ---------------------------------------------------------------------------
__global__ __launch_bounds__(256) void cvt_f32_bf16(
    const float* __restrict__ src, unsigned short* __restrict__ dst, long long n)
{
  const long long i0 = ((long long)blockIdx.x * 256 + threadIdx.x) * 8;
  const long long stride = (long long)gridDim.x * 2048;
  for (long long i = i0; i < n; i += stride) {
    const float4 a = *(const float4*)(src + i);
    const float4 b = *(const float4*)(src + i + 4);
    bf16x8 o;
    o[0] = (short)f2b(a.x); o[1] = (short)f2b(a.y);
    o[2] = (short)f2b(a.z); o[3] = (short)f2b(a.w);
    o[4] = (short)f2b(b.x); o[5] = (short)f2b(b.y);
    o[6] = (short)f2b(b.z); o[7] = (short)f2b(b.w);
    *(bf16x8*)(dst + i) = o;
  }
}

// ---------------------------------------------------------------------------
// C[M,N] = A[M,K] @ W[N,K]^T (+bias), bf16 in, fp32 accum, OutT out.
// 256x256 tile, BK=32, 512 threads (8 waves as 2x4, each owning 128x64 of C).
// v3: B (=W, 2 MB, L2-resident) is loaded DIRECTLY global->VGPR per fragment
// (reg double-buffered one K-step ahead) -- no LDS staging for B. LDS holds
// only A in a ring-3 of 16 KB buffers (48 KiB total): per-K-step LDS traffic
// drops 160 KB -> 96 KB/CU (the round-1 bottleneck). ONE barrier per K-step
// (round-1 structure, which beat the 4-barrier phase split). Counted
// vmcnt(2): retires own A-stage(t) + B(t), keeps A-stage(t+1) in flight.
// A LDS chunk-XOR swizzle with pre-swizzled GLOBAL source (linear LDS dest;
// rule 21) -- verified 0 bank conflicts in round 1. Bijective XCD-chunked
// column-fast blockIdx remap (T1, verified FETCH 850->147 MB).
// Requires: M%256==0, N%256==0, K%64==0, grid%8==0.
// ---------------------------------------------------------------------------
template <typename OutT>
__global__ __launch_bounds__(512, 2) void gemm_bt(
    const unsigned short* __restrict__ A,
    const unsigned short* __restrict__ W,
    const float* __restrict__ bias,
    OutT* __restrict__ C,
    int M, int N, int K)
{
  __shared__ __attribute__((aligned(16))) unsigned short As[3][8192];

  const int tid   = threadIdx.x;
  const int lane  = tid & 63;
  const int w     = tid >> 6;           // 0..7
  const int wr128 = (w >> 2) * 128;     // wave row offset in tile
  const int wn64  = (w & 3) * 64;       // wave col offset in tile
  const int lr    = lane & 15;
  const int lg    = lane >> 4;          // k-quarter
  const int wofs  = w * 512;            // elements: wave's linear staging slot

  // T1: bijective XCD-chunked remap; logical id is column-fast.
  const int nwg     = gridDim.x;
  const int bx      = blockIdx.x;
  const int logical = (bx & 7) * (nwg >> 3) + (bx >> 3);
  const int colsN   = N >> 8;
  const int tileM   = logical / colsN;
  const int tileN   = logical - tileM * colsN;
  const size_t rowBase = (size_t)tileM * 256;
  const int    colBase = tileN * 256;

  // A staging: thread deposits 16B at linear LDS byte tid*16 (+8192 bytes for
  // rows 128..255) = (row = tid/4 (+128), chunk = tid&3). Swizzle
  // chunk' = chunk ^ ((row>>1)&3) realized by fetching the inverse-swizzled
  // global chunk; ((row>>1)&3) == ((tid>>3)&3).
  const int sRow   = tid >> 2;                       // 0..127
  const int sChunk = (tid & 3) ^ ((tid >> 3) & 3);
  const unsigned short* Ag0 = A + (rowBase + sRow) * (size_t)K + sChunk * 8;
  const unsigned short* Ag1 = Ag0 + (size_t)128 * K;

  // B fragment row pointers: lane (lr,lg) of wave w reads, for fragment ni,
  // W[colBase + wn64 + ni*16 + lr][kt + lg*8 .. +8] -- 16 B contiguous.
  const unsigned short* Wr0 = W + ((size_t)colBase + wn64 +  0 + lr) * K + lg * 8;
  const unsigned short* Wr1 = W + ((size_t)colBase + wn64 + 16 + lr) * K + lg * 8;
  const unsigned short* Wr2 = W + ((size_t)colBase + wn64 + 32 + lr) * K + lg * 8;
  const unsigned short* Wr3 = W + ((size_t)colBase + wn64 + 48 + lr) * K + lg * 8;

  f32x4 acc[8][4] = {};
  const int nt = K >> 5;  // K-steps of 32

  bf16x8 bA0, bA1, bA2, bA3, bB0, bB1, bB2, bB3;

  // Prologue: stage A tile 0,1 (2 gloads each); B(0) into bA.
  gload_lds16(Ag0, &As[0][0] + wofs);
  gload_lds16(Ag1, &As[0][0] + wofs + 4096);
  bA0 = *(const bf16x8*)(Wr0);
  bA1 = *(const bf16x8*)(Wr1);
  bA2 = *(const bf16x8*)(Wr2);
  bA3 = *(const bf16x8*)(Wr3);
  gload_lds16(Ag0 + 32, &As[1][0] + wofs);
  gload_lds16(Ag1 + 32, &As[1][0] + wofs + 4096);

  // Per K-step t (A buffer t%3, B regs BCUR loaded at iter t-1):
  //   vmcnt(VM): own A-stage(t) + B(t) retired; A-stage(t+1) stays in flight.
  //   barrier: all waves' A-stage(t) visible; buffer (t+2)%3's old reads
  //            (tile t-1, lgkm-drained by its MFMA uses) are done.
  //   issue B(t+1) -> BNXT (plain loads, compiler-tracked waits),
  //   issue A-stage(t+2), 8x ds_read af, 32 MFMA (compiler interleaves
  //   lgkmcnt(7..0) so MFMA starts when af[0] lands; B already in regs).
#define GITER(T, BC0, BC1, BC2, BC3, BN0, BN1, BN2, BN3, VM)                  \
  do {                                                                        \
    asm volatile("s_waitcnt vmcnt(" VM ")" ::: "memory");                     \
    __builtin_amdgcn_s_barrier();                                             \
    __builtin_amdgcn_sched_barrier(0);                                        \
    if ((T) + 1 < nt) {                                                       \
      const int ko = ((T) + 1) * 32;                                          \
      BN0 = *(const bf16x8*)(Wr0 + ko);                                       \
      BN1 = *(const bf16x8*)(Wr1 + ko);                                       \
      BN2 = *(const bf16x8*)(Wr2 + ko);                                       \
      BN3 = *(const bf16x8*)(Wr3 + ko);                                       \
    }                                                                         \
    if ((T) + 2 < nt) {                                                       \
      const int wb = ((T) + 2) % 3;                                           \
      const size_t ke = (size_t)((T) + 2) * 32;                               \
      gload_lds16(Ag0 + ke, &As[wb][0] + wofs);                               \
      gload_lds16(Ag1 + ke, &As[wb][0] + wofs + 4096);                        \
    }                                                                         \
    const unsigned short* asb = &As[(T) % 3][0];                              \
    bf16x8 af[8];                                                             \
    _Pragma("unroll")                                                         \
    for (int mi = 0; mi < 8; ++mi) {                                          \
      const int row = wr128 + mi * 16 + lr;                                   \
      af[mi] = *(const bf16x8*)(asb + row * 32 + (lg ^ ((row >> 1) & 3)) * 8);\
    }                                                                         \
    _Pragma("unroll")                                                         \
    for (int mi = 0; mi < 8; ++mi) {                                          \
      acc[mi][0] = MFMA16(af[mi], BC0, acc[mi][0]);                           \
      acc[mi][1] = MFMA16(af[mi], BC1, acc[mi][1]);                           \
      acc[mi][2] = MFMA16(af[mi], BC2, acc[mi][2]);                           \
      acc[mi][3] = MFMA16(af[mi], BC3, acc[mi][3]);                           \
    }                                                                         \
  } while (0)

  for (int t = 0; t < nt - 2; t += 2) {
    GITER(t,     bA0, bA1, bA2, bA3, bB0, bB1, bB2, bB3, "2");
    GITER(t + 1, bB0, bB1, bB2, bB3, bA0, bA1, bA2, bA3, "2");
  }
  GITER(nt - 2, bA0, bA1, bA2, bA3, bB0, bB1, bB2, bB3, "2");
  GITER(nt - 1, bB0, bB1, bB2, bB3, bA0, bA1, bA2, bA3, "0");
#undef GITER

  // Epilogue (register-only; no barrier needed).
  const int rg = lg * 4;
#pragma unroll
  for (int ni = 0; ni < 4; ++ni) {
    const int col = colBase + wn64 + ni * 16 + lr;
    const float bv = bias ? bias[col] : 0.0f;
#pragma unroll
    for (int mi = 0; mi < 8; ++mi) {
#pragma unroll
      for (int r = 0; r < 4; ++r) {
        const size_t row = rowBase + wr128 + mi * 16 + rg + r;
        const float val = acc[mi][ni][r] + bv;
        if constexpr (std::is_same_v<OutT, float>) C[row * (size_t)N + col] = val;
        else                                       C[row * (size_t)N + col] = f2b(val);
      }
    }
  }
}

// ---------------------------------------------------------------------------
// Attention pass 1 (yz half): block = (i,b,a,h). 64 queries j, 64 keys k
// (same a, second spatial axis). Writes unnormalized O1 (bf16) + m1,l1 (fp32).
// ---------------------------------------------------------------------------
__global__ __launch_bounds__(256) void attn_yz(
    const unsigned short* __restrict__ Q,
    const unsigned short* __restrict__ Kx,
    const unsigned short* __restrict__ Vx,
    unsigned short* __restrict__ O1,
    float* __restrict__ m1s, float* __restrict__ l1s)
{
  __shared__ __attribute__((aligned(16))) unsigned short Qs[4096], Ks[4096], Vs[4096], Ps[4096];

  const int bid = blockIdx.x;
  const int h = bid & 15;
  const int a = (bid >> 4) & 63;
  const int b = (bid >> 10) & 7;
  const int i = bid >> 13;
  const int i1 = (i + 1) % 3;

  const size_t qoff = ((size_t)((b * 3 + i) * 4096 + a * 64)) * 1024 + h * 64;
  const size_t koff = ((size_t)((b * 3 + i1) * 4096 + a * 64)) * 1024 + h * 64;

  const int tid = threadIdx.x;
#pragma unroll
  for (int it = 0; it < 2; ++it) {
    const int idx = it * 2048 + tid * 8;
    const int row = idx >> 6, col = idx & 63;
    const int d = swz(row, col);
    *(bf16x8*)&Qs[d] = *(const bf16x8*)(Q + qoff + (size_t)row * 1024 + col);
    *(bf16x8*)&Ks[d] = *(const bf16x8*)(Kx + koff + (size_t)row * 1024 + col);
    *(bf16x8*)&Vs[d] = *(const bf16x8*)(Vx + koff + (size_t)row * 1024 + col);
  }
  __syncthreads();

  const int lane = tid & 63;
  const int w  = tid >> 6;
  const int lr = lane & 15;
  const int lg = lane >> 4;

  // S = Q @ K^T ; wave w owns query rows j = w*16..w*16+15
  f32x4 sa[4] = {};
  {
    const bf16x8 aq0 = *(const bf16x8*)&Qs[swz(w * 16 + lr, lg * 8)];
    const bf16x8 aq1 = *(const bf16x8*)&Qs[swz(w * 16 + lr, 32 + lg * 8)];
#pragma unroll
    for (int nf = 0; nf < 4; ++nf) {
      const bf16x8 bk0 = *(const bf16x8*)&Ks[swz(nf * 16 + lr, lg * 8)];
      const bf16x8 bk1 = *(const bf16x8*)&Ks[swz(nf * 16 + lr, 32 + lg * 8)];
      sa[nf] = MFMA16(aq0, bk0, sa[nf]);
      sa[nf] = MFMA16(aq1, bk1, sa[nf]);
    }
  }

  const float scale = 0.125f;
  float m[4], ls[4];
#pragma unroll
  for (int r = 0; r < 4; ++r) {
#pragma unroll
    for (int nf = 0; nf < 4; ++nf) sa[nf][r] *= scale;
    float v = fmaxf(fmaxf(sa[0][r], sa[1][r]), fmaxf(sa[2][r], sa[3][r]));
    v = fmaxf(v, __shfl_xor(v, 1));
    v = fmaxf(v, __shfl_xor(v, 2));
    v = fmaxf(v, __shfl_xor(v, 4));
    v = fmaxf(v, __shfl_xor(v, 8));
    m[r] = v;
    float s = 0.0f;
#pragma unroll
    for (int nf = 0; nf < 4; ++nf) { const float p = __expf(sa[nf][r] - v); sa[nf][r] = p; s += p; }
    s += __shfl_xor(s, 1);
    s += __shfl_xor(s, 2);
    s += __shfl_xor(s, 4);
    s += __shfl_xor(s, 8);
    ls[r] = s;
  }

#pragma unroll
  for (int nf = 0; nf < 4; ++nf)
#pragma unroll
    for (int r = 0; r < 4; ++r)
      Ps[swz(w * 16 + lg * 4 + r, nf * 16 + lr)] = f2b(sa[nf][r]);

  if (lr == 0) {
    const size_t sb = ((size_t)(i * 8 + b) * 16 + h) * 4096 + a * 64 + w * 16 + lg * 4;
#pragma unroll
    for (int r = 0; r < 4; ++r) { m1s[sb + r] = m[r]; l1s[sb + r] = ls[r]; }
  }
  __syncthreads();

  // O1u = P @ V
  f32x4 oa[4] = {};
#pragma unroll
  for (int ks = 0; ks < 2; ++ks) {
    const bf16x8 ap = *(const bf16x8*)&Ps[swz(w * 16 + lr, ks * 32 + lg * 8)];
#pragma unroll
    for (int df = 0; df < 4; ++df) {
      bf16x8 bv;
#pragma unroll
      for (int e = 0; e < 8; ++e)
        bv[e] = (short)Vs[swz(ks * 32 + lg * 8 + e, df * 16 + lr)];
      oa[df] = MFMA16(ap, bv, oa[df]);
    }
  }

  const size_t ob = ((size_t)(i * 8 + b) * 4096 + a * 64) * 1024 + h * 64;
#pragma unroll
  for (int df = 0; df < 4; ++df)
#pragma unroll
    for (int r = 0; r < 4; ++r)
      O1[ob + (size_t)(w * 16 + lg * 4 + r) * 1024 + df * 16 + lr] = f2b(oa[df][r]);
}

// ---------------------------------------------------------------------------
// Attention pass 2 (zx half, keys along first spatial axis at fixed j)
// + online-softmax combine in place in O1.
// ---------------------------------------------------------------------------
__global__ __launch_bounds__(256) void attn_zx(
    const unsigned short* __restrict__ Q,
    const unsigned short* __restrict__ Kx,
    const unsigned short* __restrict__ Vx,
    unsigned short* __restrict__ O1,
    const float* __restrict__ m1s, const float* __restrict__ l1s)
{
  __shared__ __attribute__((aligned(16))) unsigned short Qs[4096], Ks[4096], Vs[4096], Ps[4096];

  const int bid = blockIdx.x;
  const int j = bid & 63;
  const int h = (bid >> 6) & 15;
  const int b = (bid >> 10) & 7;
  const int i = bid >> 13;
  const int i2 = (i + 2) % 3;

  const size_t qoff = ((size_t)(b * 3 + i) * 4096 + j) * 1024 + h * 64;
  const size_t koff = ((size_t)(b * 3 + i2) * 4096 + j) * 1024 + h * 64;
  const size_t rstride = 65536;  // 64 rows * 1024 cols

  const int tid = threadIdx.x;
#pragma unroll
  for (int it = 0; it < 2; ++it) {
    const int idx = it * 2048 + tid * 8;
    const int row = idx >> 6, col = idx & 63;
    const int d = swz(row, col);
    *(bf16x8*)&Qs[d] = *(const bf16x8*)(Q + qoff + (size_t)row * rstride + col);
    *(bf16x8*)&Ks[d] = *(const bf16x8*)(Kx + koff + (size_t)row * rstride + col);
    *(bf16x8*)&Vs[d] = *(const bf16x8*)(Vx + koff + (size_t)row * rstride + col);
  }
  __syncthreads();

  const int lane = tid & 63;
  const int w  = tid >> 6;
  const int lr = lane & 15;
  const int lg = lane >> 4;

  f32x4 sa[4] = {};
  {
    const bf16x8 aq0 = *(const bf16x8*)&Qs[swz(w * 16 + lr, lg * 8)];
    const bf16x8 aq1 = *(const bf16x8*)&Qs[swz(w * 16 + lr, 32 + lg * 8)];
#pragma unroll
    for (int nf = 0; nf < 4; ++nf) {
      const bf16x8 bk0 = *(const bf16x8*)&Ks[swz(nf * 16 + lr, lg * 8)];
      const bf16x8 bk1 = *(const bf16x8*)&Ks[swz(nf * 16 + lr, 32 + lg * 8)];
      sa[nf] = MFMA16(aq0, bk0, sa[nf]);
      sa[nf] = MFMA16(aq1, bk1, sa[nf]);
    }
  }

  const float scale = 0.125f;
  float m[4], ls[4];
#pragma unroll
  for (int r = 0; r < 4; ++r) {
#pragma unroll
    for (int nf = 0; nf < 4; ++nf) sa[nf][r] *= scale;
    float v = fmaxf(fmaxf(sa[0][r], sa[1][r]), fmaxf(sa[2][r], sa[3][r]));
    v = fmaxf(v, __shfl_xor(v, 1));
    v = fmaxf(v, __shfl_xor(v, 2));
    v = fmaxf(v, __shfl_xor(v, 4));
    v = fmaxf(v, __shfl_xor(v, 8));
    m[r] = v;
    float s = 0.0f;
#pragma unroll
    for (int nf = 0; nf < 4; ++nf) { const float p = __expf(sa[nf][r] - v); sa[nf][r] = p; s += p; }
    s += __shfl_xor(s, 1);
    s += __shfl_xor(s, 2);
    s += __shfl_xor(s, 4);
    s += __shfl_xor(s, 8);
    ls[r] = s;
  }

  float c1[4], c2[4], rden[4];
  const size_t sb = ((size_t)(i * 8 + b) * 16 + h) * 4096 + j;
#pragma unroll
  for (int r = 0; r < 4; ++r) {
    const int arow = w * 16 + lg * 4 + r;
    const float mm1 = m1s[sb + (size_t)arow * 64];
    const float ll1 = l1s[sb + (size_t)arow * 64];
    const float mm = fmaxf(mm1, m[r]);
    const float e1 = __expf(mm1 - mm);
    const float e2 = __expf(m[r] - mm);
    c1[r] = e1; c2[r] = e2;
    rden[r] = 1.0f / (e1 * ll1 + e2 * ls[r]);
  }

#pragma unroll
  for (int nf = 0; nf < 4; ++nf)
#pragma unroll
    for (int r = 0; r < 4; ++r)
      Ps[swz(w * 16 + lg * 4 + r, nf * 16 + lr)] = f2b(sa[nf][r]);
  __syncthreads();

  f32x4 oa[4] = {};
#pragma unroll
  for (int ks = 0; ks < 2; ++ks) {
    const bf16x8 ap = *(const bf16x8*)&Ps[swz(w * 16 + lr, ks * 32 + lg * 8)];
#pragma unroll
    for (int df = 0; df < 4; ++df) {
      bf16x8 bv;
#pragma unroll
      for (int e = 0; e < 8; ++e)
        bv[e] = (short)Vs[swz(ks * 32 + lg * 8 + e, df * 16 + lr)];
      oa[df] = MFMA16(ap, bv, oa[df]);
    }
  }

  const size_t ob = ((size_t)(i * 8 + b) * 4096 + j) * 1024 + h * 64;
#pragma unroll
  for (int df = 0; df < 4; ++df)
#pragma unroll
    for (int r = 0; r < 4; ++r) {
      const size_t addr = ob + (size_t)(w * 16 + lg * 4 + r) * rstride + df * 16 + lr;
      const float o1v = b2f(O1[addr]);
      O1[addr] = f2b((c1[r] * o1v + c2[r] * oa[df][r]) * rden[r]);
    }
}

// ---------------------------------------------------------------------------
extern "C" void kernel_launch(void* const* d_in, const int* in_sizes, int n_in,
                              void* d_out, int out_size, void* d_ws, size_t ws_size,
                              hipStream_t stream)
{
  const float* x  = (const float*)d_in[0];
  const float* wq = (const float*)d_in[1];
  const float* wk = (const float*)d_in[2];
  const float* wv = (const float*)d_in[3];
  const float* wp = (const float*)d_in[4];
  const float* bp = (const float*)d_in[5];

  const int M = 98304, N = 1024, K = 1024;
  const size_t SLAB = 201326592ull;   // 98304*1024*2 bytes (bf16 slab)
  const size_t STAT = 6291456ull;     // 3*8*16*4096 floats

  char* ws = (char*)d_ws;
  unsigned short* xb  = (unsigned short*)(ws);            // converted x; reused as O1 after QKV
  unsigned short* Kb  = (unsigned short*)(ws + SLAB);
  unsigned short* Vb  = (unsigned short*)(ws + 2 * SLAB);
  float* m1s          = (float*)(ws + 3 * SLAB);
  float* l1s          = (float*)(ws + 3 * SLAB + STAT);
  unsigned short* wqb = (unsigned short*)(ws + 3 * SLAB + 2 * STAT);
  unsigned short* wkb = wqb + 1048576;
  unsigned short* wvb = wkb + 1048576;
  unsigned short* wpb = wvb + 1048576;
  unsigned short* Qb  = (unsigned short*)d_out;  // bf16 Q scratch in fp32 d_out; dead before final write
  unsigned short* O1  = xb;                      // x slab dead after the three QKV GEMMs

  dim3 blk(256);
  cvt_f32_bf16<<<dim3(4096), blk, 0, stream>>>(x,  xb,  (long long)M * 1024);
  cvt_f32_bf16<<<dim3(512),  blk, 0, stream>>>(wq, wqb, 1048576);
  cvt_f32_bf16<<<dim3(512),  blk, 0, stream>>>(wk, wkb, 1048576);
  cvt_f32_bf16<<<dim3(512),  blk, 0, stream>>>(wv, wvb, 1048576);
  cvt_f32_bf16<<<dim3(512),  blk, 0, stream>>>(wp, wpb, 1048576);

  dim3 gg((M / 256) * (N / 256));   // 1536 blocks, % 8 == 0 (bijective XCD remap)
  dim3 gblk(512);
  gemm_bt<unsigned short><<<gg, gblk, 0, stream>>>(xb, wqb, (const float*)nullptr, Qb, M, N, K);
  gemm_bt<unsigned short><<<gg, gblk, 0, stream>>>(xb, wkb, (const float*)nullptr, Kb, M, N, K);
  gemm_bt<unsigned short><<<gg, gblk, 0, stream>>>(xb, wvb, (const float*)nullptr, Vb, M, N, K);
  attn_yz<<<dim3(24576), blk, 0, stream>>>(Qb, Kb, Vb, O1, m1s, l1s);
  attn_zx<<<dim3(24576), blk, 0, stream>>>(Qb, Kb, Vb, O1, m1s, l1s);
  gemm_bt<float><<<gg, gblk, 0, stream>>>(O1, wpb, bp, (float*)d_out, M, N, K);
}

// Round 4
// 1445.145 us; speedup vs baseline: 1.3743x; 1.3743x over previous
//
#include <hip/hip_runtime.h>
#include <hip/hip_bf16.h>
#include <stdint.h>
#include <type_traits>

typedef __hip_bfloat16 hbf16;
typedef short bf16x8 __attribute__((ext_vector_type(8)));
typedef float f32x4 __attribute__((ext_vector_type(4)));
typedef unsigned int u32x4 __attribute__((ext_vector_type(4)));

#define MFMA16(a, b, c) __builtin_amdgcn_mfma_f32_16x16x32_bf16((a), (b), (c), 0, 0, 0)

__device__ __forceinline__ void gload_lds16(const void* g, void* l) {
  __builtin_amdgcn_global_load_lds(
      (const __attribute__((address_space(1))) void*)g,
      (__attribute__((address_space(3))) void*)l, 16, 0, 0);
}

__device__ __forceinline__ float b2f(unsigned short u) {
  union { unsigned int u32; float f; } cv;
  cv.u32 = ((unsigned int)u) << 16;
  return cv.f;
}
__device__ __forceinline__ unsigned short f2b(float f) {
  hbf16 h = __float2bfloat16(f);
  return __builtin_bit_cast(unsigned short, h);
}

// element-index XOR swizzle for 64-col bf16 LDS tiles (attn kernels)
__device__ __forceinline__ int swz(int row, int col) {
  return row * 64 + (col ^ ((row & 7) << 3));
}

// ---------------------------------------------------------------------------
// fp32 -> bf16 conversion. n must be a multiple of 8.
// ---------------------------------------------------------------------------
__global__ __launch_bounds__(256) void cvt_f32_bf16(
    const float* __restrict__ src, unsigned short* __restrict__ dst, long long n)
{
  const long long i0 = ((long long)blockIdx.x * 256 + threadIdx.x) * 8;
  const long long stride = (long long)gridDim.x * 2048;
  for (long long i = i0; i < n; i += stride) {
    const float4 a = *(const float4*)(src + i);
    const float4 b = *(const float4*)(src + i + 4);
    bf16x8 o;
    o[0] = (short)f2b(a.x); o[1] = (short)f2b(a.y);
    o[2] = (short)f2b(a.z); o[3] = (short)f2b(a.w);
    o[4] = (short)f2b(b.x); o[5] = (short)f2b(b.y);
    o[6] = (short)f2b(b.z); o[7] = (short)f2b(b.w);
    *(bf16x8*)(dst + i) = o;
  }
}

// ---------------------------------------------------------------------------
// C[M,N] = A[M,K] @ W[N,K]^T (+bias), bf16 in, fp32 accum, OutT out.
// v4: 256x128 tile, BK=32, 512 threads (8 waves as 4x2, each owning 64x64).
// Ring-3 LDS (3 x (16KB A + 8KB B) = 72 KiB) -> 2 blocks/CU: restores the
// m114 cross-block MFMA/staging overlap that the round-1 single-block
// lockstep structurally lacked, while keeping big-tile low traffic.
// Round-1-verified skeleton otherwise: ONE counted vmcnt(3) + ONE barrier
// per K-step, global_load_lds staging (3 loads/tile: 2 A + 1 B), chunk-XOR
// LDS swizzle realized via pre-swizzled GLOBAL source (rule 21; 0 bank
// conflicts verified), bijective column-fast XCD remap (A fetched once/XCD).
// New: LDS-staged coalesced epilogue (per-wave private region, 16B/lane
// contiguous stores) to kill the 2.5x WRITE_SIZE amplification.
// Requires: M%256==0, N%128==0, K%32==0, K>=96, grid%8==0.
// ---------------------------------------------------------------------------
template <typename OutT>
__global__ __launch_bounds__(512, 4) void gemm_bt(
    const unsigned short* __restrict__ A,
    const unsigned short* __restrict__ W,
    const float* __restrict__ bias,
    OutT* __restrict__ C,
    int M, int N, int K)
{
  // 72 KiB: A ring = Sm[0 .. 24575] (3 x 8192 shorts), B ring = Sm[24576 ..]
  __shared__ __attribute__((aligned(16))) unsigned short Sm[36864];

  const int tid  = threadIdx.x;
  const int lane = tid & 63;
  const int w    = tid >> 6;            // 0..7
  const int wr64 = (w >> 1) * 64;       // wave row offset (4 groups)
  const int wc64 = (w & 1) * 64;        // wave col offset (2 groups)
  const int lr   = lane & 15;
  const int lg   = lane >> 4;           // k-quarter
  const int wofs = w * 512;             // shorts: wave's 1KB staging slot

  // T1: bijective XCD-chunked remap; logical id is column-fast.
  const int nwg     = gridDim.x;
  const int bx      = blockIdx.x;
  const int logical = (bx & 7) * (nwg >> 3) + (bx >> 3);
  const int colsN   = N >> 7;           // N/128
  const int tileM   = logical / colsN;
  const int tileN   = logical - tileM * colsN;
  const size_t rowBase = (size_t)tileM * 256;
  const int    colBase = tileN * 128;

  // Staging: thread deposits 16B at linear LDS byte tid*16 within each 8KB
  // half (row = tid/4, chunk = tid&3). Swizzle chunk' = chunk ^ ((row>>1)&3)
  // realized by fetching the inverse-swizzled global chunk;
  // ((row>>1)&3) == ((tid>>3)&3).
  const int sRow   = tid >> 2;                       // 0..127
  const int sChunk = (tid & 3) ^ ((tid >> 3) & 3);
  const unsigned short* Ag0 = A + (rowBase + sRow) * (size_t)K + sChunk * 8;
  const unsigned short* Ag1 = Ag0 + (size_t)128 * K;
  const unsigned short* Wg0 = W + ((size_t)colBase + sRow) * K + sChunk * 8;

  f32x4 acc[4][4] = {};
  const int nt = K >> 5;  // K-steps of 32

  // Prologue: stage tiles 0,1 (3 gloads each -> 6 in flight per wave).
#pragma unroll
  for (int p = 0; p < 2; ++p) {
    const size_t ke = (size_t)p * 32;
    gload_lds16(Ag0 + ke, Sm + p * 8192 + wofs);
    gload_lds16(Ag1 + ke, Sm + p * 8192 + 4096 + wofs);
    gload_lds16(Wg0 + ke, Sm + 24576 + p * 4096 + wofs);
  }

  // Per K-step t (buffer t%3):
  //   vmcnt(3): own tile-t loads retired; tile t+1's 3 stay in flight. [T4]
  //   barrier: all waves' tile-t staged; buffer (t+2)%3's reads (tile t-1,
  //            done in window t-1) retired -> free to restage.
  //   stage tile t+2, 8x ds_read_b128 (4 af + 4 bf), 16 MFMA; compiler
  //   interleaves lgkmcnt(7..0) with the MFMA cluster.
#define GITER(T, VM, STG)                                                     \
  do {                                                                        \
    asm volatile("s_waitcnt vmcnt(" VM ")" ::: "memory");                     \
    __builtin_amdgcn_s_barrier();                                             \
    __builtin_amdgcn_sched_barrier(0);                                        \
    if (STG) {                                                                \
      const int nb = ((T) + 2) % 3;                                           \
      const size_t ke = (size_t)((T) + 2) * 32;                               \
      gload_lds16(Ag0 + ke, Sm + nb * 8192 + wofs);                           \
      gload_lds16(Ag1 + ke, Sm + nb * 8192 + 4096 + wofs);                    \
      gload_lds16(Wg0 + ke, Sm + 24576 + nb * 4096 + wofs);                   \
    }                                                                         \
    const unsigned short* asb = Sm + ((T) % 3) * 8192;                        \
    const unsigned short* bsb = Sm + 24576 + ((T) % 3) * 4096;                \
    bf16x8 af[4], bfv[4];                                                     \
    _Pragma("unroll")                                                         \
    for (int mi = 0; mi < 4; ++mi) {                                          \
      const int row = wr64 + mi * 16 + lr;                                    \
      af[mi] = *(const bf16x8*)(asb + row * 32 + (lg ^ ((row >> 1) & 3)) * 8);\
    }                                                                         \
    _Pragma("unroll")                                                         \
    for (int ni = 0; ni < 4; ++ni) {                                          \
      const int row = wc64 + ni * 16 + lr;                                    \
      bfv[ni] = *(const bf16x8*)(bsb + row * 32 + (lg ^ ((row >> 1) & 3)) * 8);\
    }                                                                         \
    _Pragma("unroll")                                                         \
    for (int mi = 0; mi < 4; ++mi)                                            \
      _Pragma("unroll")                                                       \
      for (int ni = 0; ni < 4; ++ni)                                          \
        acc[mi][ni] = MFMA16(af[mi], bfv[ni], acc[mi][ni]);                   \
  } while (0)

  for (int t = 0; t < nt - 2; ++t) GITER(t, "3", true);
  GITER(nt - 2, "3", false);   // 6 outstanding -> drain tile nt-2
  GITER(nt - 1, "0", false);   // 3 outstanding -> drain tile nt-1
#undef GITER

  // ------------------------------------------------------------------
  // Epilogue: LDS-staged coalesced stores. Wave's 64x64 block is written
  // in 2 batches of 32 rows through a PRIVATE per-wave LDS region (no
  // cross-wave barrier inside the batch loop; in-order DS pipe + alias
  // analysis order the write->read within a wave).
  // ------------------------------------------------------------------
  __syncthreads();  // ring buffers dead; safe to reuse Sm

  float bv[4];
#pragma unroll
  for (int ni = 0; ni < 4; ++ni)
    bv[ni] = bias ? bias[colBase + wc64 + ni * 16 + lr] : 0.0f;

  const size_t R0 = rowBase + wr64;
  const int    C0 = colBase + wc64;

#pragma unroll
  for (int batch = 0; batch < 2; ++batch) {
    if constexpr (std::is_same_v<OutT, float>) {
      float* reg = (float*)(void*)Sm + w * 2048;   // 8KB per wave
#pragma unroll
      for (int mi2 = 0; mi2 < 2; ++mi2) {
        const int mi = batch * 2 + mi2;
#pragma unroll
        for (int ni = 0; ni < 4; ++ni)
#pragma unroll
          for (int r = 0; r < 4; ++r)
            reg[(mi2 * 16 + lg * 4 + r) * 64 + ni * 16 + lr] =
                acc[mi][ni][r] + bv[ni];
      }
      asm volatile("s_waitcnt lgkmcnt(0)" ::: "memory");
      __builtin_amdgcn_sched_barrier(0);
#pragma unroll
      for (int it = 0; it < 8; ++it) {
        const int ch  = it * 64 + lane;       // 16B chunks: 32 rows x 16
        const int row = ch >> 4, cc = ch & 15;
        const float4 v = *(const float4*)(reg + row * 64 + cc * 4);
        *(float4*)((float*)C + (R0 + batch * 32 + row) * (size_t)N + C0 + cc * 4) = v;
      }
    } else {
      unsigned short* reg = Sm + w * 2048;         // 4KB per wave
#pragma unroll
      for (int mi2 = 0; mi2 < 2; ++mi2) {
        const int mi = batch * 2 + mi2;
#pragma unroll
        for (int ni = 0; ni < 4; ++ni)
#pragma unroll
          for (int r = 0; r < 4; ++r)
            reg[(mi2 * 16 + lg * 4 + r) * 64 + ni * 16 + lr] =
                f2b(acc[mi][ni][r] + bv[ni]);
      }
      asm volatile("s_waitcnt lgkmcnt(0)" ::: "memory");
      __builtin_amdgcn_sched_barrier(0);
#pragma unroll
      for (int it = 0; it < 4; ++it) {
        const int ch  = it * 64 + lane;       // 16B chunks: 32 rows x 8
        const int row = ch >> 3, cc = ch & 7;
        const u32x4 v = *(const u32x4*)(reg + row * 64 + cc * 8);
        *(u32x4*)((unsigned short*)C + (R0 + batch * 32 + row) * (size_t)N + C0 + cc * 8) = v;
      }
    }
  }
}

// ---------------------------------------------------------------------------
// Attention pass 1 (yz half): block = (i,b,a,h). 64 queries j, 64 keys k
// (same a, second spatial axis). Writes unnormalized O1 (bf16) + m1,l1 (fp32).
// ---------------------------------------------------------------------------
__global__ __launch_bounds__(256) void attn_yz(
    const unsigned short* __restrict__ Q,
    const unsigned short* __restrict__ Kx,
    const unsigned short* __restrict__ Vx,
    unsigned short* __restrict__ O1,
    float* __restrict__ m1s, float* __restrict__ l1s)
{
  __shared__ __attribute__((aligned(16))) unsigned short Qs[4096], Ks[4096], Vs[4096], Ps[4096];

  const int bid = blockIdx.x;
  const int h = bid & 15;
  const int a = (bid >> 4) & 63;
  const int b = (bid >> 10) & 7;
  const int i = bid >> 13;
  const int i1 = (i + 1) % 3;

  const size_t qoff = ((size_t)((b * 3 + i) * 4096 + a * 64)) * 1024 + h * 64;
  const size_t koff = ((size_t)((b * 3 + i1) * 4096 + a * 64)) * 1024 + h * 64;

  const int tid = threadIdx.x;
#pragma unroll
  for (int it = 0; it < 2; ++it) {
    const int idx = it * 2048 + tid * 8;
    const int row = idx >> 6, col = idx & 63;
    const int d = swz(row, col);
    *(bf16x8*)&Qs[d] = *(const bf16x8*)(Q + qoff + (size_t)row * 1024 + col);
    *(bf16x8*)&Ks[d] = *(const bf16x8*)(Kx + koff + (size_t)row * 1024 + col);
    *(bf16x8*)&Vs[d] = *(const bf16x8*)(Vx + koff + (size_t)row * 1024 + col);
  }
  __syncthreads();

  const int lane = tid & 63;
  const int w  = tid >> 6;
  const int lr = lane & 15;
  const int lg = lane >> 4;

  // S = Q @ K^T ; wave w owns query rows j = w*16..w*16+15
  f32x4 sa[4] = {};
  {
    const bf16x8 aq0 = *(const bf16x8*)&Qs[swz(w * 16 + lr, lg * 8)];
    const bf16x8 aq1 = *(const bf16x8*)&Qs[swz(w * 16 + lr, 32 + lg * 8)];
#pragma unroll
    for (int nf = 0; nf < 4; ++nf) {
      const bf16x8 bk0 = *(const bf16x8*)&Ks[swz(nf * 16 + lr, lg * 8)];
      const bf16x8 bk1 = *(const bf16x8*)&Ks[swz(nf * 16 + lr, 32 + lg * 8)];
      sa[nf] = MFMA16(aq0, bk0, sa[nf]);
      sa[nf] = MFMA16(aq1, bk1, sa[nf]);
    }
  }

  const float scale = 0.125f;
  float m[4], ls[4];
#pragma unroll
  for (int r = 0; r < 4; ++r) {
#pragma unroll
    for (int nf = 0; nf < 4; ++nf) sa[nf][r] *= scale;
    float v = fmaxf(fmaxf(sa[0][r], sa[1][r]), fmaxf(sa[2][r], sa[3][r]));
    v = fmaxf(v, __shfl_xor(v, 1));
    v = fmaxf(v, __shfl_xor(v, 2));
    v = fmaxf(v, __shfl_xor(v, 4));
    v = fmaxf(v, __shfl_xor(v, 8));
    m[r] = v;
    float s = 0.0f;
#pragma unroll
    for (int nf = 0; nf < 4; ++nf) { const float p = __expf(sa[nf][r] - v); sa[nf][r] = p; s += p; }
    s += __shfl_xor(s, 1);
    s += __shfl_xor(s, 2);
    s += __shfl_xor(s, 4);
    s += __shfl_xor(s, 8);
    ls[r] = s;
  }

#pragma unroll
  for (int nf = 0; nf < 4; ++nf)
#pragma unroll
    for (int r = 0; r < 4; ++r)
      Ps[swz(w * 16 + lg * 4 + r, nf * 16 + lr)] = f2b(sa[nf][r]);

  if (lr == 0) {
    const size_t sb = ((size_t)(i * 8 + b) * 16 + h) * 4096 + a * 64 + w * 16 + lg * 4;
#pragma unroll
    for (int r = 0; r < 4; ++r) { m1s[sb + r] = m[r]; l1s[sb + r] = ls[r]; }
  }
  __syncthreads();

  // O1u = P @ V
  f32x4 oa[4] = {};
#pragma unroll
  for (int ks = 0; ks < 2; ++ks) {
    const bf16x8 ap = *(const bf16x8*)&Ps[swz(w * 16 + lr, ks * 32 + lg * 8)];
#pragma unroll
    for (int df = 0; df < 4; ++df) {
      bf16x8 bv;
#pragma unroll
      for (int e = 0; e < 8; ++e)
        bv[e] = (short)Vs[swz(ks * 32 + lg * 8 + e, df * 16 + lr)];
      oa[df] = MFMA16(ap, bv, oa[df]);
    }
  }

  const size_t ob = ((size_t)(i * 8 + b) * 4096 + a * 64) * 1024 + h * 64;
#pragma unroll
  for (int df = 0; df < 4; ++df)
#pragma unroll
    for (int r = 0; r < 4; ++r)
      O1[ob + (size_t)(w * 16 + lg * 4 + r) * 1024 + df * 16 + lr] = f2b(oa[df][r]);
}

// ---------------------------------------------------------------------------
// Attention pass 2 (zx half, keys along first spatial axis at fixed j)
// + online-softmax combine in place in O1.
// ---------------------------------------------------------------------------
__global__ __launch_bounds__(256) void attn_zx(
    const unsigned short* __restrict__ Q,
    const unsigned short* __restrict__ Kx,
    const unsigned short* __restrict__ Vx,
    unsigned short* __restrict__ O1,
    const float* __restrict__ m1s, const float* __restrict__ l1s)
{
  __shared__ __attribute__((aligned(16))) unsigned short Qs[4096], Ks[4096], Vs[4096], Ps[4096];

  const int bid = blockIdx.x;
  const int j = bid & 63;
  const int h = (bid >> 6) & 15;
  const int b = (bid >> 10) & 7;
  const int i = bid >> 13;
  const int i2 = (i + 2) % 3;

  const size_t qoff = ((size_t)(b * 3 + i) * 4096 + j) * 1024 + h * 64;
  const size_t koff = ((size_t)(b * 3 + i2) * 4096 + j) * 1024 + h * 64;
  const size_t rstride = 65536;  // 64 rows * 1024 cols

  const int tid = threadIdx.x;
#pragma unroll
  for (int it = 0; it < 2; ++it) {
    const int idx = it * 2048 + tid * 8;
    const int row = idx >> 6, col = idx & 63;
    const int d = swz(row, col);
    *(bf16x8*)&Qs[d] = *(const bf16x8*)(Q + qoff + (size_t)row * rstride + col);
    *(bf16x8*)&Ks[d] = *(const bf16x8*)(Kx + koff + (size_t)row * rstride + col);
    *(bf16x8*)&Vs[d] = *(const bf16x8*)(Vx + koff + (size_t)row * rstride + col);
  }
  __syncthreads();

  const int lane = tid & 63;
  const int w  = tid >> 6;
  const int lr = lane & 15;
  const int lg = lane >> 4;

  f32x4 sa[4] = {};
  {
    const bf16x8 aq0 = *(const bf16x8*)&Qs[swz(w * 16 + lr, lg * 8)];
    const bf16x8 aq1 = *(const bf16x8*)&Qs[swz(w * 16 + lr, 32 + lg * 8)];
#pragma unroll
    for (int nf = 0; nf < 4; ++nf) {
      const bf16x8 bk0 = *(const bf16x8*)&Ks[swz(nf * 16 + lr, lg * 8)];
      const bf16x8 bk1 = *(const bf16x8*)&Ks[swz(nf * 16 + lr, 32 + lg * 8)];
      sa[nf] = MFMA16(aq0, bk0, sa[nf]);
      sa[nf] = MFMA16(aq1, bk1, sa[nf]);
    }
  }

  const float scale = 0.125f;
  float m[4], ls[4];
#pragma unroll
  for (int r = 0; r < 4; ++r) {
#pragma unroll
    for (int nf = 0; nf < 4; ++nf) sa[nf][r] *= scale;
    float v = fmaxf(fmaxf(sa[0][r], sa[1][r]), fmaxf(sa[2][r], sa[3][r]));
    v = fmaxf(v, __shfl_xor(v, 1));
    v = fmaxf(v, __shfl_xor(v, 2));
    v = fmaxf(v, __shfl_xor(v, 4));
    v = fmaxf(v, __shfl_xor(v, 8));
    m[r] = v;
    float s = 0.0f;
#pragma unroll
    for (int nf = 0; nf < 4; ++nf) { const float p = __expf(sa[nf][r] - v); sa[nf][r] = p; s += p; }
    s += __shfl_xor(s, 1);
    s += __shfl_xor(s, 2);
    s += __shfl_xor(s, 4);
    s += __shfl_xor(s, 8);
    ls[r] = s;
  }

  float c1[4], c2[4], rden[4];
  const size_t sb = ((size_t)(i * 8 + b) * 16 + h) * 4096 + j;
#pragma unroll
  for (int r = 0; r < 4; ++r) {
    const int arow = w * 16 + lg * 4 + r;
    const float mm1 = m1s[sb + (size_t)arow * 64];
    const float ll1 = l1s[sb + (size_t)arow * 64];
    const float mm = fmaxf(mm1, m[r]);
    const float e1 = __expf(mm1 - mm);
    const float e2 = __expf(m[r] - mm);
    c1[r] = e1; c2[r] = e2;
    rden[r] = 1.0f / (e1 * ll1 + e2 * ls[r]);
  }

#pragma unroll
  for (int nf = 0; nf < 4; ++nf)
#pragma unroll
    for (int r = 0; r < 4; ++r)
      Ps[swz(w * 16 + lg * 4 + r, nf * 16 + lr)] = f2b(sa[nf][r]);
  __syncthreads();

  f32x4 oa[4] = {};
#pragma unroll
  for (int ks = 0; ks < 2; ++ks) {
    const bf16x8 ap = *(const bf16x8*)&Ps[swz(w * 16 + lr, ks * 32 + lg * 8)];
#pragma unroll
    for (int df = 0; df < 4; ++df) {
      bf16x8 bv;
#pragma unroll
      for (int e = 0; e < 8; ++e)
        bv[e] = (short)Vs[swz(ks * 32 + lg * 8 + e, df * 16 + lr)];
      oa[df] = MFMA16(ap, bv, oa[df]);
    }
  }

  const size_t ob = ((size_t)(i * 8 + b) * 4096 + j) * 1024 + h * 64;
#pragma unroll
  for (int df = 0; df < 4; ++df)
#pragma unroll
    for (int r = 0; r < 4; ++r) {
      const size_t addr = ob + (size_t)(w * 16 + lg * 4 + r) * rstride + df * 16 + lr;
      const float o1v = b2f(O1[addr]);
      O1[addr] = f2b((c1[r] * o1v + c2[r] * oa[df][r]) * rden[r]);
    }
}

// ---------------------------------------------------------------------------
extern "C" void kernel_launch(void* const* d_in, const int* in_sizes, int n_in,
                              void* d_out, int out_size, void* d_ws, size_t ws_size,
                              hipStream_t stream)
{
  const float* x  = (const float*)d_in[0];
  const float* wq = (const float*)d_in[1];
  const float* wk = (const float*)d_in[2];
  const float* wv = (const float*)d_in[3];
  const float* wp = (const float*)d_in[4];
  const float* bp = (const float*)d_in[5];

  const int M = 98304, N = 1024, K = 1024;
  const size_t SLAB = 201326592ull;   // 98304*1024*2 bytes (bf16 slab)
  const size_t STAT = 6291456ull;     // 3*8*16*4096 floats

  char* ws = (char*)d_ws;
  unsigned short* xb  = (unsigned short*)(ws);            // converted x; reused as O1 after QKV
  unsigned short* Kb  = (unsigned short*)(ws + SLAB);
  unsigned short* Vb  = (unsigned short*)(ws + 2 * SLAB);
  float* m1s          = (float*)(ws + 3 * SLAB);
  float* l1s          = (float*)(ws + 3 * SLAB + STAT);
  unsigned short* wqb = (unsigned short*)(ws + 3 * SLAB + 2 * STAT);
  unsigned short* wkb = wqb + 1048576;
  unsigned short* wvb = wkb + 1048576;
  unsigned short* wpb = wvb + 1048576;
  unsigned short* Qb  = (unsigned short*)d_out;  // bf16 Q scratch in fp32 d_out; dead before final write
  unsigned short* O1  = xb;                      // x slab dead after the three QKV GEMMs

  dim3 blk(256);
  cvt_f32_bf16<<<dim3(4096), blk, 0, stream>>>(x,  xb,  (long long)M * 1024);
  cvt_f32_bf16<<<dim3(512),  blk, 0, stream>>>(wq, wqb, 1048576);
  cvt_f32_bf16<<<dim3(512),  blk, 0, stream>>>(wk, wkb, 1048576);
  cvt_f32_bf16<<<dim3(512),  blk, 0, stream>>>(wv, wvb, 1048576);
  cvt_f32_bf16<<<dim3(512),  blk, 0, stream>>>(wp, wpb, 1048576);

  dim3 gg((M / 256) * (N / 128));   // 3072 blocks, % 8 == 0 (bijective XCD remap)
  dim3 gblk(512);
  gemm_bt<unsigned short><<<gg, gblk, 0, stream>>>(xb, wqb, (const float*)nullptr, Qb, M, N, K);
  gemm_bt<unsigned short><<<gg, gblk, 0, stream>>>(xb, wkb, (const float*)nullptr, Kb, M, N, K);
  gemm_bt<unsigned short><<<gg, gblk, 0, stream>>>(xb, wvb, (const float*)nullptr, Vb, M, N, K);
  attn_yz<<<dim3(24576), blk, 0, stream>>>(Qb, Kb, Vb, O1, m1s, l1s);
  attn_zx<<<dim3(24576), blk, 0, stream>>>(Qb, Kb, Vb, O1, m1s, l1s);
  gemm_bt<float><<<gg, gblk, 0, stream>>>(O1, wpb, bp, (float*)d_out, M, N, K);
}

// Round 5
// 1411.442 us; speedup vs baseline: 1.4071x; 1.0239x over previous
//
#include <hip/hip_runtime.h>
#include <hip/hip_bf16.h>
#include <stdint.h>
#include <type_traits>

typedef __hip_bfloat16 hbf16;
typedef short bf16x8 __attribute__((ext_vector_type(8)));
typedef float f32x4 __attribute__((ext_vector_type(4)));
typedef unsigned int u32x4 __attribute__((ext_vector_type(4)));

#define MFMA16(a, b, c) __builtin_amdgcn_mfma_f32_16x16x32_bf16((a), (b), (c), 0, 0, 0)

__device__ __forceinline__ void gload_lds16(const void* g, void* l) {
  __builtin_amdgcn_global_load_lds(
      (const __attribute__((address_space(1))) void*)g,
      (__attribute__((address_space(3))) void*)l, 16, 0, 0);
}

__device__ __forceinline__ float b2f(unsigned short u) {
  union { unsigned int u32; float f; } cv;
  cv.u32 = ((unsigned int)u) << 16;
  return cv.f;
}
__device__ __forceinline__ unsigned short f2b(float f) {
  hbf16 h = __float2bfloat16(f);
  return __builtin_bit_cast(unsigned short, h);
}

// element-index XOR swizzle for 64-col bf16 LDS tiles (attn kernels)
__device__ __forceinline__ int swz(int row, int col) {
  return row * 64 + (col ^ ((row & 7) << 3));
}

// ---------------------------------------------------------------------------
// fp32 -> bf16 conversion. n must be a multiple of 8.
// ---------------------------------------------------------------------------
__global__ __launch_bounds__(256) void cvt_f32_bf16(
    const float* __restrict__ src, unsigned short* __restrict__ dst, long long n)
{
  const long long i0 = ((long long)blockIdx.x * 256 + threadIdx.x) * 8;
  const long long stride = (long long)gridDim.x * 2048;
  for (long long i = i0; i < n; i += stride) {
    const float4 a = *(const float4*)(src + i);
    const float4 b = *(const float4*)(src + i + 4);
    bf16x8 o;
    o[0] = (short)f2b(a.x); o[1] = (short)f2b(a.y);
    o[2] = (short)f2b(a.z); o[3] = (short)f2b(a.w);
    o[4] = (short)f2b(b.x); o[5] = (short)f2b(b.y);
    o[6] = (short)f2b(b.z); o[7] = (short)f2b(b.w);
    *(bf16x8*)(dst + i) = o;
  }
}

// Four 1024x1024 weight matrices in one launch; dst slabs contiguous.
__global__ __launch_bounds__(256) void cvt4_w(
    const float* __restrict__ s0, const float* __restrict__ s1,
    const float* __restrict__ s2, const float* __restrict__ s3,
    unsigned short* __restrict__ dst)
{
  const int q = blockIdx.x >> 9;
  const float* src = (q == 0) ? s0 : (q == 1) ? s1 : (q == 2) ? s2 : s3;
  const long long i = ((long long)(blockIdx.x & 511) * 256 + threadIdx.x) * 8;
  const float4 a = *(const float4*)(src + i);
  const float4 b = *(const float4*)(src + i + 4);
  bf16x8 o;
  o[0] = (short)f2b(a.x); o[1] = (short)f2b(a.y);
  o[2] = (short)f2b(a.z); o[3] = (short)f2b(a.w);
  o[4] = (short)f2b(b.x); o[5] = (short)f2b(b.y);
  o[6] = (short)f2b(b.z); o[7] = (short)f2b(b.w);
  *(bf16x8*)(dst + (long long)q * 1048576 + i) = o;
}

// ---------------------------------------------------------------------------
// Fused QKV GEMM: C[:,n] for n in [0,3072) against W3=[wq;wk;wv] (N,K)^T,
// routed to Cq/Ck/Cv slabs (each M x 1024, bf16).
// 256x128 tile, BK=32, 256 threads (4 waves as 2x2, each owning 128x64).
// Theory: round-4 was LDS-read-bound (operand replication 64KB/tile at 4x2
// waves). 2x2 grid reads A 2x + B 2x = 48KB/tile (-25%). Same ring-3 LDS
// (72 KiB -> 2 blocks/CU), counted vmcnt(6) (6 gloads/step/wave), ONE
// barrier per K-step, chunk-XOR swizzle via pre-swizzled global source
// (0 bank conflicts, verified). Bijective column-fast XCD remap.
// Epilogue: wave-pairs stage 128x128 bf16 panels in LDS (bank-swizzled),
// cooperatively store full 256B rows (HBM write granule -- fp32 proj showed
// exact writes at 256B chunks, bf16 at 128B showed 2x amplification).
// Requires: M%256==0, Ntot%128==0 (slab-aligned: 1024|colBase routing ok
// since 128|1024), K%32==0, K>=96, grid%8==0.
// ---------------------------------------------------------------------------
__global__ __launch_bounds__(256, 2) void gemm_qkv(
    const unsigned short* __restrict__ A,
    const unsigned short* __restrict__ W,
    unsigned short* __restrict__ Cq,
    unsigned short* __restrict__ Ck,
    unsigned short* __restrict__ Cv,
    int M, int Ntot, int K)
{
  // ring-3: A buffers 3 x 8192 shorts (16KB), B buffers 3 x 4096 shorts (8KB)
  __shared__ __attribute__((aligned(16))) unsigned short Sm[36864];

  const int tid  = threadIdx.x;
  const int lane = tid & 63;
  const int w    = tid >> 6;            // 0..3
  const int wr   = w >> 1;              // 0..1: row half (128 rows)
  const int wc   = w & 1;               // 0..1: col half (64 cols)
  const int lr   = lane & 15;
  const int lg   = lane >> 4;

  const int nwg     = gridDim.x;
  const int bx      = blockIdx.x;
  const int logical = (bx & 7) * (nwg >> 3) + (bx >> 3);
  const int colsN   = Ntot >> 7;
  const int tileM   = logical / colsN;
  const int tileN   = logical - tileM * colsN;
  const size_t rowBase = (size_t)tileM * 256;
  const int    colBase = tileN * 128;

  // Staging: 256 threads, chunk ci = c*256 + tid deposits 16B at linear LDS
  // byte ci*16 = (row = ci>>2 = c*64 + tid>>2, kchunk = tid&3). Swizzle
  // chunk' = chunk ^ ((row>>1)&3) realized by inverse-swizzled global chunk;
  // (row>>1)&3 == (ci>>3)&3 == (tid>>3)&3 (c*32 == 0 mod 4).
  const int sRow   = tid >> 2;                       // 0..63
  const int sChunk = (tid & 3) ^ ((tid >> 3) & 3);
  const unsigned short* Ag0 = A + (rowBase +   0 + sRow) * (size_t)K + sChunk * 8;
  const unsigned short* Ag1 = A + (rowBase +  64 + sRow) * (size_t)K + sChunk * 8;
  const unsigned short* Ag2 = A + (rowBase + 128 + sRow) * (size_t)K + sChunk * 8;
  const unsigned short* Ag3 = A + (rowBase + 192 + sRow) * (size_t)K + sChunk * 8;
  const unsigned short* Wg0 = W + ((size_t)colBase +  0 + sRow) * K + sChunk * 8;
  const unsigned short* Wg1 = W + ((size_t)colBase + 64 + sRow) * K + sChunk * 8;

  f32x4 acc[8][4] = {};
  const int nt = K >> 5;

  // Prologue: stage tiles 0,1 (6 gloads each -> 12 in flight per wave).
#pragma unroll
  for (int p = 0; p < 2; ++p) {
    const size_t ke = (size_t)p * 32;
    unsigned short* ab = Sm + p * 8192;
    unsigned short* bb = Sm + 24576 + p * 4096;
    gload_lds16(Ag0 + ke, ab +        w * 512);
    gload_lds16(Ag1 + ke, ab + 2048 + w * 512);
    gload_lds16(Ag2 + ke, ab + 4096 + w * 512);
    gload_lds16(Ag3 + ke, ab + 6144 + w * 512);
    gload_lds16(Wg0 + ke, bb +        w * 512);
    gload_lds16(Wg1 + ke, bb + 2048 + w * 512);
  }

#define QITER(T, VM, STG)                                                     \
  do {                                                                        \
    asm volatile("s_waitcnt vmcnt(" VM ")" ::: "memory");                     \
    __builtin_amdgcn_s_barrier();                                             \
    __builtin_amdgcn_sched_barrier(0);                                        \
    if (STG) {                                                                \
      const int nb = ((T) + 2) % 3;                                           \
      const size_t ke = (size_t)((T) + 2) * 32;                               \
      unsigned short* ab = Sm + nb * 8192;                                    \
      unsigned short* bb = Sm + 24576 + nb * 4096;                            \
      gload_lds16(Ag0 + ke, ab +        w * 512);                             \
      gload_lds16(Ag1 + ke, ab + 2048 + w * 512);                             \
      gload_lds16(Ag2 + ke, ab + 4096 + w * 512);                             \
      gload_lds16(Ag3 + ke, ab + 6144 + w * 512);                             \
      gload_lds16(Wg0 + ke, bb +        w * 512);                             \
      gload_lds16(Wg1 + ke, bb + 2048 + w * 512);                             \
    }                                                                         \
    const unsigned short* asb = Sm + ((T) % 3) * 8192;                        \
    const unsigned short* bsb = Sm + 24576 + ((T) % 3) * 4096;                \
    bf16x8 af[8], bfv[4];                                                     \
    _Pragma("unroll")                                                         \
    for (int mi = 0; mi < 8; ++mi) {                                          \
      const int row = wr * 128 + mi * 16 + lr;                                \
      af[mi] = *(const bf16x8*)(asb + row * 32 + (lg ^ ((row >> 1) & 3)) * 8);\
    }                                                                         \
    _Pragma("unroll")                                                         \
    for (int ni = 0; ni < 4; ++ni) {                                          \
      const int row = wc * 64 + ni * 16 + lr;                                 \
      bfv[ni] = *(const bf16x8*)(bsb + row * 32 + (lg ^ ((row >> 1) & 3)) * 8);\
    }                                                                         \
    _Pragma("unroll")                                                         \
    for (int mi = 0; mi < 8; ++mi)                                            \
      _Pragma("unroll")                                                       \
      for (int ni = 0; ni < 4; ++ni)                                          \
        acc[mi][ni] = MFMA16(af[mi], bfv[ni], acc[mi][ni]);                   \
  } while (0)

  for (int t = 0; t < nt - 2; ++t) QITER(t, "6", true);
  QITER(nt - 2, "6", false);
  QITER(nt - 1, "0", false);
#undef QITER

  // Epilogue: pair (wr,0)+(wr,1) stages a 128x128 bf16 panel, then writes
  // full rows (256B contiguous) cooperatively.
  __syncthreads();
  unsigned short* G = Sm + wr * 16384;
#pragma unroll
  for (int mi = 0; mi < 8; ++mi)
#pragma unroll
    for (int ni = 0; ni < 4; ++ni)
#pragma unroll
      for (int r = 0; r < 4; ++r) {
        const int row = mi * 16 + lg * 4 + r;
        const int c   = wc * 64 + ni * 16 + lr;
        G[row * 128 + (c ^ (((row >> 2) & 3) << 4))] = f2b(acc[mi][ni][r]);
      }
  __syncthreads();

  const int out = colBase >> 10;
  unsigned short* Co = (out == 0) ? Cq : (out == 1) ? Ck : Cv;
  const int colLocal = colBase & 1023;
#pragma unroll
  for (int it = 0; it < 16; ++it) {
    const int ch  = it * 128 + wc * 64 + lane;   // 2048 chunks: 128 rows x 16
    const int row = ch >> 4, cc = ch & 15;
    const u32x4 v = *(const u32x4*)(G + row * 128 + ((cc * 8) ^ (((row >> 2) & 3) << 4)));
    *(u32x4*)(Co + (rowBase + wr * 128 + row) * 1024 + colLocal + cc * 8) = v;
  }
}

// ---------------------------------------------------------------------------
// Proj GEMM (fp32 out) -- round-4 kernel kept EXACTLY as the control arm.
// 256x128 tile, BK=32, 512 threads (8 waves as 4x2, each owning 64x64).
// ---------------------------------------------------------------------------
template <typename OutT>
__global__ __launch_bounds__(512, 4) void gemm_bt(
    const unsigned short* __restrict__ A,
    const unsigned short* __restrict__ W,
    const float* __restrict__ bias,
    OutT* __restrict__ C,
    int M, int N, int K)
{
  __shared__ __attribute__((aligned(16))) unsigned short Sm[36864];

  const int tid  = threadIdx.x;
  const int lane = tid & 63;
  const int w    = tid >> 6;
  const int wr64 = (w >> 1) * 64;
  const int wc64 = (w & 1) * 64;
  const int lr   = lane & 15;
  const int lg   = lane >> 4;
  const int wofs = w * 512;

  const int nwg     = gridDim.x;
  const int bx      = blockIdx.x;
  const int logical = (bx & 7) * (nwg >> 3) + (bx >> 3);
  const int colsN   = N >> 7;
  const int tileM   = logical / colsN;
  const int tileN   = logical - tileM * colsN;
  const size_t rowBase = (size_t)tileM * 256;
  const int    colBase = tileN * 128;

  const int sRow   = tid >> 2;
  const int sChunk = (tid & 3) ^ ((tid >> 3) & 3);
  const unsigned short* Ag0 = A + (rowBase + sRow) * (size_t)K + sChunk * 8;
  const unsigned short* Ag1 = Ag0 + (size_t)128 * K;
  const unsigned short* Wg0 = W + ((size_t)colBase + sRow) * K + sChunk * 8;

  f32x4 acc[4][4] = {};
  const int nt = K >> 5;

#pragma unroll
  for (int p = 0; p < 2; ++p) {
    const size_t ke = (size_t)p * 32;
    gload_lds16(Ag0 + ke, Sm + p * 8192 + wofs);
    gload_lds16(Ag1 + ke, Sm + p * 8192 + 4096 + wofs);
    gload_lds16(Wg0 + ke, Sm + 24576 + p * 4096 + wofs);
  }

#define GITER(T, VM, STG)                                                     \
  do {                                                                        \
    asm volatile("s_waitcnt vmcnt(" VM ")" ::: "memory");                     \
    __builtin_amdgcn_s_barrier();                                             \
    __builtin_amdgcn_sched_barrier(0);                                        \
    if (STG) {                                                                \
      const int nb = ((T) + 2) % 3;                                           \
      const size_t ke = (size_t)((T) + 2) * 32;                               \
      gload_lds16(Ag0 + ke, Sm + nb * 8192 + wofs);                           \
      gload_lds16(Ag1 + ke, Sm + nb * 8192 + 4096 + wofs);                    \
      gload_lds16(Wg0 + ke, Sm + 24576 + nb * 4096 + wofs);                   \
    }                                                                         \
    const unsigned short* asb = Sm + ((T) % 3) * 8192;                        \
    const unsigned short* bsb = Sm + 24576 + ((T) % 3) * 4096;                \
    bf16x8 af[4], bfv[4];                                                     \
    _Pragma("unroll")                                                         \
    for (int mi = 0; mi < 4; ++mi) {                                          \
      const int row = wr64 + mi * 16 + lr;                                    \
      af[mi] = *(const bf16x8*)(asb + row * 32 + (lg ^ ((row >> 1) & 3)) * 8);\
    }                                                                         \
    _Pragma("unroll")                                                         \
    for (int ni = 0; ni < 4; ++ni) {                                          \
      const int row = wc64 + ni * 16 + lr;                                    \
      bfv[ni] = *(const bf16x8*)(bsb + row * 32 + (lg ^ ((row >> 1) & 3)) * 8);\
    }                                                                         \
    _Pragma("unroll")                                                         \
    for (int mi = 0; mi < 4; ++mi)                                            \
      _Pragma("unroll")                                                       \
      for (int ni = 0; ni < 4; ++ni)                                          \
        acc[mi][ni] = MFMA16(af[mi], bfv[ni], acc[mi][ni]);                   \
  } while (0)

  for (int t = 0; t < nt - 2; ++t) GITER(t, "3", true);
  GITER(nt - 2, "3", false);
  GITER(nt - 1, "0", false);
#undef GITER

  __syncthreads();

  float bv[4];
#pragma unroll
  for (int ni = 0; ni < 4; ++ni)
    bv[ni] = bias ? bias[colBase + wc64 + ni * 16 + lr] : 0.0f;

  const size_t R0 = rowBase + wr64;
  const int    C0 = colBase + wc64;

#pragma unroll
  for (int batch = 0; batch < 2; ++batch) {
    if constexpr (std::is_same_v<OutT, float>) {
      float* reg = (float*)(void*)Sm + w * 2048;
#pragma unroll
      for (int mi2 = 0; mi2 < 2; ++mi2) {
        const int mi = batch * 2 + mi2;
#pragma unroll
        for (int ni = 0; ni < 4; ++ni)
#pragma unroll
          for (int r = 0; r < 4; ++r) {
            const int row = mi2 * 16 + lg * 4 + r;
            reg[row * 64 + ((ni * 16 + lr) ^ (((row >> 2) & 3) << 4))] =
                acc[mi][ni][r] + bv[ni];
          }
      }
      asm volatile("s_waitcnt lgkmcnt(0)" ::: "memory");
      __builtin_amdgcn_sched_barrier(0);
#pragma unroll
      for (int it = 0; it < 8; ++it) {
        const int ch  = it * 64 + lane;
        const int row = ch >> 4, cc = ch & 15;
        const float4 v = *(const float4*)(reg + row * 64 + ((cc * 4) ^ (((row >> 2) & 3) << 4)));
        *(float4*)((float*)C + (R0 + batch * 32 + row) * (size_t)N + C0 + cc * 4) = v;
      }
    } else {
      unsigned short* reg = Sm + w * 2048;
#pragma unroll
      for (int mi2 = 0; mi2 < 2; ++mi2) {
        const int mi = batch * 2 + mi2;
#pragma unroll
        for (int ni = 0; ni < 4; ++ni)
#pragma unroll
          for (int r = 0; r < 4; ++r)
            reg[(mi2 * 16 + lg * 4 + r) * 64 + ni * 16 + lr] =
                f2b(acc[mi][ni][r] + bv[ni]);
      }
      asm volatile("s_waitcnt lgkmcnt(0)" ::: "memory");
      __builtin_amdgcn_sched_barrier(0);
#pragma unroll
      for (int it = 0; it < 4; ++it) {
        const int ch  = it * 64 + lane;
        const int row = ch >> 3, cc = ch & 7;
        const u32x4 v = *(const u32x4*)(reg + row * 64 + cc * 8);
        *(u32x4*)((unsigned short*)C + (R0 + batch * 32 + row) * (size_t)N + C0 + cc * 8) = v;
      }
    }
  }
}

// ---------------------------------------------------------------------------
// Attention pass 1 (yz half): block = (i,b,a,h). 64 queries j, 64 keys k
// (same a, second spatial axis). Writes unnormalized O1 (bf16) + m1,l1 (fp32).
// ---------------------------------------------------------------------------
__global__ __launch_bounds__(256) void attn_yz(
    const unsigned short* __restrict__ Q,
    const unsigned short* __restrict__ Kx,
    const unsigned short* __restrict__ Vx,
    unsigned short* __restrict__ O1,
    float* __restrict__ m1s, float* __restrict__ l1s)
{
  __shared__ __attribute__((aligned(16))) unsigned short Qs[4096], Ks[4096], Vs[4096], Ps[4096];

  const int bid = blockIdx.x;
  const int h = bid & 15;
  const int a = (bid >> 4) & 63;
  const int b = (bid >> 10) & 7;
  const int i = bid >> 13;
  const int i1 = (i + 1) % 3;

  const size_t qoff = ((size_t)((b * 3 + i) * 4096 + a * 64)) * 1024 + h * 64;
  const size_t koff = ((size_t)((b * 3 + i1) * 4096 + a * 64)) * 1024 + h * 64;

  const int tid = threadIdx.x;
#pragma unroll
  for (int it = 0; it < 2; ++it) {
    const int idx = it * 2048 + tid * 8;
    const int row = idx >> 6, col = idx & 63;
    const int d = swz(row, col);
    *(bf16x8*)&Qs[d] = *(const bf16x8*)(Q + qoff + (size_t)row * 1024 + col);
    *(bf16x8*)&Ks[d] = *(const bf16x8*)(Kx + koff + (size_t)row * 1024 + col);
    *(bf16x8*)&Vs[d] = *(const bf16x8*)(Vx + koff + (size_t)row * 1024 + col);
  }
  __syncthreads();

  const int lane = tid & 63;
  const int w  = tid >> 6;
  const int lr = lane & 15;
  const int lg = lane >> 4;

  f32x4 sa[4] = {};
  {
    const bf16x8 aq0 = *(const bf16x8*)&Qs[swz(w * 16 + lr, lg * 8)];
    const bf16x8 aq1 = *(const bf16x8*)&Qs[swz(w * 16 + lr, 32 + lg * 8)];
#pragma unroll
    for (int nf = 0; nf < 4; ++nf) {
      const bf16x8 bk0 = *(const bf16x8*)&Ks[swz(nf * 16 + lr, lg * 8)];
      const bf16x8 bk1 = *(const bf16x8*)&Ks[swz(nf * 16 + lr, 32 + lg * 8)];
      sa[nf] = MFMA16(aq0, bk0, sa[nf]);
      sa[nf] = MFMA16(aq1, bk1, sa[nf]);
    }
  }

  const float scale = 0.125f;
  float m[4], ls[4];
#pragma unroll
  for (int r = 0; r < 4; ++r) {
#pragma unroll
    for (int nf = 0; nf < 4; ++nf) sa[nf][r] *= scale;
    float v = fmaxf(fmaxf(sa[0][r], sa[1][r]), fmaxf(sa[2][r], sa[3][r]));
    v = fmaxf(v, __shfl_xor(v, 1));
    v = fmaxf(v, __shfl_xor(v, 2));
    v = fmaxf(v, __shfl_xor(v, 4));
    v = fmaxf(v, __shfl_xor(v, 8));
    m[r] = v;
    float s = 0.0f;
#pragma unroll
    for (int nf = 0; nf < 4; ++nf) { const float p = __expf(sa[nf][r] - v); sa[nf][r] = p; s += p; }
    s += __shfl_xor(s, 1);
    s += __shfl_xor(s, 2);
    s += __shfl_xor(s, 4);
    s += __shfl_xor(s, 8);
    ls[r] = s;
  }

#pragma unroll
  for (int nf = 0; nf < 4; ++nf)
#pragma unroll
    for (int r = 0; r < 4; ++r)
      Ps[swz(w * 16 + lg * 4 + r, nf * 16 + lr)] = f2b(sa[nf][r]);

  if (lr == 0) {
    const size_t sb = ((size_t)(i * 8 + b) * 16 + h) * 4096 + a * 64 + w * 16 + lg * 4;
#pragma unroll
    for (int r = 0; r < 4; ++r) { m1s[sb + r] = m[r]; l1s[sb + r] = ls[r]; }
  }
  __syncthreads();

  f32x4 oa[4] = {};
#pragma unroll
  for (int ks = 0; ks < 2; ++ks) {
    const bf16x8 ap = *(const bf16x8*)&Ps[swz(w * 16 + lr, ks * 32 + lg * 8)];
#pragma unroll
    for (int df = 0; df < 4; ++df) {
      bf16x8 bv;
#pragma unroll
      for (int e = 0; e < 8; ++e)
        bv[e] = (short)Vs[swz(ks * 32 + lg * 8 + e, df * 16 + lr)];
      oa[df] = MFMA16(ap, bv, oa[df]);
    }
  }

  const size_t ob = ((size_t)(i * 8 + b) * 4096 + a * 64) * 1024 + h * 64;
#pragma unroll
  for (int df = 0; df < 4; ++df)
#pragma unroll
    for (int r = 0; r < 4; ++r)
      O1[ob + (size_t)(w * 16 + lg * 4 + r) * 1024 + df * 16 + lr] = f2b(oa[df][r]);
}

// ---------------------------------------------------------------------------
// Attention pass 2 (zx half) + online-softmax combine in place in O1.
// ---------------------------------------------------------------------------
__global__ __launch_bounds__(256) void attn_zx(
    const unsigned short* __restrict__ Q,
    const unsigned short* __restrict__ Kx,
    const unsigned short* __restrict__ Vx,
    unsigned short* __restrict__ O1,
    const float* __restrict__ m1s, const float* __restrict__ l1s)
{
  __shared__ __attribute__((aligned(16))) unsigned short Qs[4096], Ks[4096], Vs[4096], Ps[4096];

  const int bid = blockIdx.x;
  const int j = bid & 63;
  const int h = (bid >> 6) & 15;
  const int b = (bid >> 10) & 7;
  const int i = bid >> 13;
  const int i2 = (i + 2) % 3;

  const size_t qoff = ((size_t)(b * 3 + i) * 4096 + j) * 1024 + h * 64;
  const size_t koff = ((size_t)(b * 3 + i2) * 4096 + j) * 1024 + h * 64;
  const size_t rstride = 65536;

  const int tid = threadIdx.x;
#pragma unroll
  for (int it = 0; it < 2; ++it) {
    const int idx = it * 2048 + tid * 8;
    const int row = idx >> 6, col = idx & 63;
    const int d = swz(row, col);
    *(bf16x8*)&Qs[d] = *(const bf16x8*)(Q + qoff + (size_t)row * rstride + col);
    *(bf16x8*)&Ks[d] = *(const bf16x8*)(Kx + koff + (size_t)row * rstride + col);
    *(bf16x8*)&Vs[d] = *(const bf16x8*)(Vx + koff + (size_t)row * rstride + col);
  }
  __syncthreads();

  const int lane = tid & 63;
  const int w  = tid >> 6;
  const int lr = lane & 15;
  const int lg = lane >> 4;

  f32x4 sa[4] = {};
  {
    const bf16x8 aq0 = *(const bf16x8*)&Qs[swz(w * 16 + lr, lg * 8)];
    const bf16x8 aq1 = *(const bf16x8*)&Qs[swz(w * 16 + lr, 32 + lg * 8)];
#pragma unroll
    for (int nf = 0; nf < 4; ++nf) {
      const bf16x8 bk0 = *(const bf16x8*)&Ks[swz(nf * 16 + lr, lg * 8)];
      const bf16x8 bk1 = *(const bf16x8*)&Ks[swz(nf * 16 + lr, 32 + lg * 8)];
      sa[nf] = MFMA16(aq0, bk0, sa[nf]);
      sa[nf] = MFMA16(aq1, bk1, sa[nf]);
    }
  }

  const float scale = 0.125f;
  float m[4], ls[4];
#pragma unroll
  for (int r = 0; r < 4; ++r) {
#pragma unroll
    for (int nf = 0; nf < 4; ++nf) sa[nf][r] *= scale;
    float v = fmaxf(fmaxf(sa[0][r], sa[1][r]), fmaxf(sa[2][r], sa[3][r]));
    v = fmaxf(v, __shfl_xor(v, 1));
    v = fmaxf(v, __shfl_xor(v, 2));
    v = fmaxf(v, __shfl_xor(v, 4));
    v = fmaxf(v, __shfl_xor(v, 8));
    m[r] = v;
    float s = 0.0f;
#pragma unroll
    for (int nf = 0; nf < 4; ++nf) { const float p = __expf(sa[nf][r] - v); sa[nf][r] = p; s += p; }
    s += __shfl_xor(s, 1);
    s += __shfl_xor(s, 2);
    s += __shfl_xor(s, 4);
    s += __shfl_xor(s, 8);
    ls[r] = s;
  }

  float c1[4], c2[4], rden[4];
  const size_t sb = ((size_t)(i * 8 + b) * 16 + h) * 4096 + j;
#pragma unroll
  for (int r = 0; r < 4; ++r) {
    const int arow = w * 16 + lg * 4 + r;
    const float mm1 = m1s[sb + (size_t)arow * 64];
    const float ll1 = l1s[sb + (size_t)arow * 64];
    const float mm = fmaxf(mm1, m[r]);
    const float e1 = __expf(mm1 - mm);
    const float e2 = __expf(m[r] - mm);
    c1[r] = e1; c2[r] = e2;
    rden[r] = 1.0f / (e1 * ll1 + e2 * ls[r]);
  }

#pragma unroll
  for (int nf = 0; nf < 4; ++nf)
#pragma unroll
    for (int r = 0; r < 4; ++r)
      Ps[swz(w * 16 + lg * 4 + r, nf * 16 + lr)] = f2b(sa[nf][r]);
  __syncthreads();

  f32x4 oa[4] = {};
#pragma unroll
  for (int ks = 0; ks < 2; ++ks) {
    const bf16x8 ap = *(const bf16x8*)&Ps[swz(w * 16 + lr, ks * 32 + lg * 8)];
#pragma unroll
    for (int df = 0; df < 4; ++df) {
      bf16x8 bv;
#pragma unroll
      for (int e = 0; e < 8; ++e)
        bv[e] = (short)Vs[swz(ks * 32 + lg * 8 + e, df * 16 + lr)];
      oa[df] = MFMA16(ap, bv, oa[df]);
    }
  }

  const size_t ob = ((size_t)(i * 8 + b) * 4096 + j) * 1024 + h * 64;
#pragma unroll
  for (int df = 0; df < 4; ++df)
#pragma unroll
    for (int r = 0; r < 4; ++r) {
      const size_t addr = ob + (size_t)(w * 16 + lg * 4 + r) * rstride + df * 16 + lr;
      const float o1v = b2f(O1[addr]);
      O1[addr] = f2b((c1[r] * o1v + c2[r] * oa[df][r]) * rden[r]);
    }
}

// ---------------------------------------------------------------------------
extern "C" void kernel_launch(void* const* d_in, const int* in_sizes, int n_in,
                              void* d_out, int out_size, void* d_ws, size_t ws_size,
                              hipStream_t stream)
{
  const float* x  = (const float*)d_in[0];
  const float* wq = (const float*)d_in[1];
  const float* wk = (const float*)d_in[2];
  const float* wv = (const float*)d_in[3];
  const float* wp = (const float*)d_in[4];
  const float* bp = (const float*)d_in[5];

  const int M = 98304, N = 1024, K = 1024;
  const size_t SLAB = 201326592ull;   // 98304*1024*2 bytes (bf16 slab)
  const size_t STAT = 6291456ull;     // 3*8*16*4096 floats

  char* ws = (char*)d_ws;
  unsigned short* xb  = (unsigned short*)(ws);            // converted x; reused as O1 after QKV
  unsigned short* Kb  = (unsigned short*)(ws + SLAB);
  unsigned short* Vb  = (unsigned short*)(ws + 2 * SLAB);
  float* m1s          = (float*)(ws + 3 * SLAB);
  float* l1s          = (float*)(ws + 3 * SLAB + STAT);
  unsigned short* wqb = (unsigned short*)(ws + 3 * SLAB + 2 * STAT);  // [wq;wk;wv;wp] contiguous
  unsigned short* wpb = wqb + 3145728;
  unsigned short* Qb  = (unsigned short*)d_out;  // bf16 Q scratch in fp32 d_out; dead before final write
  unsigned short* O1  = xb;                      // x slab dead after the fused QKV GEMM

  dim3 blk(256);
  cvt_f32_bf16<<<dim3(4096), blk, 0, stream>>>(x, xb, (long long)M * 1024);
  cvt4_w<<<dim3(2048), blk, 0, stream>>>(wq, wk, wv, wp, wqb);

  // Fused QKV: A @ [wq;wk;wv]^T -> Qb,Kb,Vb.  grid = 384*24 = 9216 (%8==0)
  gemm_qkv<<<dim3((M / 256) * (3072 / 128)), dim3(256), 0, stream>>>(
      xb, wqb, Qb, Kb, Vb, M, 3072, K);

  attn_yz<<<dim3(24576), blk, 0, stream>>>(Qb, Kb, Vb, O1, m1s, l1s);
  attn_zx<<<dim3(24576), blk, 0, stream>>>(Qb, Kb, Vb, O1, m1s, l1s);

  // Proj (control arm: round-4 kernel unchanged). grid = 384*8 = 3072
  gemm_bt<float><<<dim3((M / 256) * (N / 128)), dim3(512), 0, stream>>>(
      O1, wpb, bp, (float*)d_out, M, N, K);
}

// Round 6
// 1390.392 us; speedup vs baseline: 1.4285x; 1.0151x over previous
//
#include <hip/hip_runtime.h>
#include <hip/hip_bf16.h>
#include <stdint.h>
#include <type_traits>

typedef __hip_bfloat16 hbf16;
typedef short bf16x8 __attribute__((ext_vector_type(8)));
typedef float f32x4 __attribute__((ext_vector_type(4)));
typedef unsigned int u32x4 __attribute__((ext_vector_type(4)));

#define MFMA16(a, b, c) __builtin_amdgcn_mfma_f32_16x16x32_bf16((a), (b), (c), 0, 0, 0)

__device__ __forceinline__ void gload_lds16(const void* g, void* l) {
  __builtin_amdgcn_global_load_lds(
      (const __attribute__((address_space(1))) void*)g,
      (__attribute__((address_space(3))) void*)l, 16, 0, 0);
}

__device__ __forceinline__ float b2f(unsigned short u) {
  union { unsigned int u32; float f; } cv;
  cv.u32 = ((unsigned int)u) << 16;
  return cv.f;
}
__device__ __forceinline__ unsigned short f2b(float f) {
  hbf16 h = __float2bfloat16(f);
  return __builtin_bit_cast(unsigned short, h);
}

// element-index XOR swizzle for 64-col bf16 LDS tiles (attn kernels)
__device__ __forceinline__ int swz(int row, int col) {
  return row * 64 + (col ^ ((row & 7) << 3));
}

// ---------------------------------------------------------------------------
// fp32 -> bf16 conversion. n must be a multiple of 8.
// ---------------------------------------------------------------------------
__global__ __launch_bounds__(256) void cvt_f32_bf16(
    const float* __restrict__ src, unsigned short* __restrict__ dst, long long n)
{
  const long long i0 = ((long long)blockIdx.x * 256 + threadIdx.x) * 8;
  const long long stride = (long long)gridDim.x * 2048;
  for (long long i = i0; i < n; i += stride) {
    const float4 a = *(const float4*)(src + i);
    const float4 b = *(const float4*)(src + i + 4);
    bf16x8 o;
    o[0] = (short)f2b(a.x); o[1] = (short)f2b(a.y);
    o[2] = (short)f2b(a.z); o[3] = (short)f2b(a.w);
    o[4] = (short)f2b(b.x); o[5] = (short)f2b(b.y);
    o[6] = (short)f2b(b.z); o[7] = (short)f2b(b.w);
    *(bf16x8*)(dst + i) = o;
  }
}

// Four 1024x1024 weight matrices in one launch; dst slabs contiguous.
__global__ __launch_bounds__(256) void cvt4_w(
    const float* __restrict__ s0, const float* __restrict__ s1,
    const float* __restrict__ s2, const float* __restrict__ s3,
    unsigned short* __restrict__ dst)
{
  const int q = blockIdx.x >> 9;
  const float* src = (q == 0) ? s0 : (q == 1) ? s1 : (q == 2) ? s2 : s3;
  const long long i = ((long long)(blockIdx.x & 511) * 256 + threadIdx.x) * 8;
  const float4 a = *(const float4*)(src + i);
  const float4 b = *(const float4*)(src + i + 4);
  bf16x8 o;
  o[0] = (short)f2b(a.x); o[1] = (short)f2b(a.y);
  o[2] = (short)f2b(a.z); o[3] = (short)f2b(a.w);
  o[4] = (short)f2b(b.x); o[5] = (short)f2b(b.y);
  o[6] = (short)f2b(b.z); o[7] = (short)f2b(b.w);
  *(bf16x8*)(dst + (long long)q * 1048576 + i) = o;
}

// ---------------------------------------------------------------------------
// Fused QKV GEMM: C[:,n] for n in [0,3072) against W3=[wq;wk;wv] (N,K)^T,
// routed to Cq/Ck/Cv slabs (each M x 1024, bf16).
// 256x128 tile, BK=32, 256 threads (4 waves as 2x2, each owning 128x64).
// Ring-3 LDS (72 KiB -> 2 blocks/CU), counted vmcnt(6), ONE barrier per
// K-step, chunk-XOR swizzle via pre-swizzled global source (0 bank
// conflicts, verified). 256B-granule LDS-staged epilogue (WRITE_SIZE
// verified exact in round 5).
// Round-6 remap: tileN PARTITIONED across XCDs. Round-5's column-fast remap
// streamed all 24 W-panels (6.3 MB > 4 MB L2) per tileM row -> W thrashed
// L2 -> FETCH 1.08 GB (5x ideal). Now XCD x owns tileN in {3x..3x+2}
// (W slice 768 KB, permanently L2-resident; fetched once per XCD) and all
// 8 XCDs sweep tileM 0..383 in the SAME order, tileN-inner -> leading
// XCD's A fetch populates L3, others hit it -> A ~once from HBM.
// Requires: M%256==0, Ntot==3072, K%32==0, K>=96, grid==8*(M/256)*3.
// ---------------------------------------------------------------------------
__global__ __launch_bounds__(256, 2) void gemm_qkv(
    const unsigned short* __restrict__ A,
    const unsigned short* __restrict__ W,
    unsigned short* __restrict__ Cq,
    unsigned short* __restrict__ Ck,
    unsigned short* __restrict__ Cv,
    int M, int Ntot, int K)
{
  // ring-3: A buffers 3 x 8192 shorts (16KB), B buffers 3 x 4096 shorts (8KB)
  __shared__ __attribute__((aligned(16))) unsigned short Sm[36864];

  const int tid  = threadIdx.x;
  const int lane = tid & 63;
  const int w    = tid >> 6;            // 0..3
  const int wr   = w >> 1;              // 0..1: row half (128 rows)
  const int wc   = w & 1;               // 0..1: col half (64 cols)
  const int lr   = lane & 15;
  const int lg   = lane >> 4;

  // XCD-partitioned-tileN remap (bijective): xcd owns 3 adjacent tileN,
  // sweeps all tileM rows tileN-inner, same tileM order on every XCD.
  const int bx    = blockIdx.x;
  const int xcd   = bx & 7;
  const int idx   = bx >> 3;            // 0 .. (M/256)*3 - 1
  const int tileN = xcd * 3 + idx % 3;
  const int tileM = idx / 3;
  const size_t rowBase = (size_t)tileM * 256;
  const int    colBase = tileN * 128;

  // Staging: 256 threads, chunk ci = c*256 + tid deposits 16B at linear LDS
  // byte ci*16 = (row = ci>>2 = c*64 + tid>>2, kchunk = tid&3). Swizzle
  // chunk' = chunk ^ ((row>>1)&3) realized by inverse-swizzled global chunk;
  // (row>>1)&3 == (ci>>3)&3 == (tid>>3)&3 (c*32 == 0 mod 4).
  const int sRow   = tid >> 2;                       // 0..63
  const int sChunk = (tid & 3) ^ ((tid >> 3) & 3);
  const unsigned short* Ag0 = A + (rowBase +   0 + sRow) * (size_t)K + sChunk * 8;
  const unsigned short* Ag1 = A + (rowBase +  64 + sRow) * (size_t)K + sChunk * 8;
  const unsigned short* Ag2 = A + (rowBase + 128 + sRow) * (size_t)K + sChunk * 8;
  const unsigned short* Ag3 = A + (rowBase + 192 + sRow) * (size_t)K + sChunk * 8;
  const unsigned short* Wg0 = W + ((size_t)colBase +  0 + sRow) * K + sChunk * 8;
  const unsigned short* Wg1 = W + ((size_t)colBase + 64 + sRow) * K + sChunk * 8;

  f32x4 acc[8][4] = {};
  const int nt = K >> 5;

  // Prologue: stage tiles 0,1 (6 gloads each -> 12 in flight per wave).
#pragma unroll
  for (int p = 0; p < 2; ++p) {
    const size_t ke = (size_t)p * 32;
    unsigned short* ab = Sm + p * 8192;
    unsigned short* bb = Sm + 24576 + p * 4096;
    gload_lds16(Ag0 + ke, ab +        w * 512);
    gload_lds16(Ag1 + ke, ab + 2048 + w * 512);
    gload_lds16(Ag2 + ke, ab + 4096 + w * 512);
    gload_lds16(Ag3 + ke, ab + 6144 + w * 512);
    gload_lds16(Wg0 + ke, bb +        w * 512);
    gload_lds16(Wg1 + ke, bb + 2048 + w * 512);
  }

#define QITER(T, VM, STG)                                                     \
  do {                                                                        \
    asm volatile("s_waitcnt vmcnt(" VM ")" ::: "memory");                     \
    __builtin_amdgcn_s_barrier();                                             \
    __builtin_amdgcn_sched_barrier(0);                                        \
    if (STG) {                                                                \
      const int nb = ((T) + 2) % 3;                                           \
      const size_t ke = (size_t)((T) + 2) * 32;                               \
      unsigned short* ab = Sm + nb * 8192;                                    \
      unsigned short* bb = Sm + 24576 + nb * 4096;                            \
      gload_lds16(Ag0 + ke, ab +        w * 512);                             \
      gload_lds16(Ag1 + ke, ab + 2048 + w * 512);                             \
      gload_lds16(Ag2 + ke, ab + 4096 + w * 512);                             \
      gload_lds16(Ag3 + ke, ab + 6144 + w * 512);                             \
      gload_lds16(Wg0 + ke, bb +        w * 512);                             \
      gload_lds16(Wg1 + ke, bb + 2048 + w * 512);                             \
    }                                                                         \
    const unsigned short* asb = Sm + ((T) % 3) * 8192;                        \
    const unsigned short* bsb = Sm + 24576 + ((T) % 3) * 4096;                \
    bf16x8 af[8], bfv[4];                                                     \
    _Pragma("unroll")                                                         \
    for (int mi = 0; mi < 8; ++mi) {                                          \
      const int row = wr * 128 + mi * 16 + lr;                                \
      af[mi] = *(const bf16x8*)(asb + row * 32 + (lg ^ ((row >> 1) & 3)) * 8);\
    }                                                                         \
    _Pragma("unroll")                                                         \
    for (int ni = 0; ni < 4; ++ni) {                                          \
      const int row = wc * 64 + ni * 16 + lr;                                 \
      bfv[ni] = *(const bf16x8*)(bsb + row * 32 + (lg ^ ((row >> 1) & 3)) * 8);\
    }                                                                         \
    _Pragma("unroll")                                                         \
    for (int mi = 0; mi < 8; ++mi)                                            \
      _Pragma("unroll")                                                       \
      for (int ni = 0; ni < 4; ++ni)                                          \
        acc[mi][ni] = MFMA16(af[mi], bfv[ni], acc[mi][ni]);                   \
  } while (0)

  for (int t = 0; t < nt - 2; ++t) QITER(t, "6", true);
  QITER(nt - 2, "6", false);
  QITER(nt - 1, "0", false);
#undef QITER

  // Epilogue: pair (wr,0)+(wr,1) stages a 128x128 bf16 panel, then writes
  // full rows (256B contiguous) cooperatively.
  __syncthreads();
  unsigned short* G = Sm + wr * 16384;
#pragma unroll
  for (int mi = 0; mi < 8; ++mi)
#pragma unroll
    for (int ni = 0; ni < 4; ++ni)
#pragma unroll
      for (int r = 0; r < 4; ++r) {
        const int row = mi * 16 + lg * 4 + r;
        const int c   = wc * 64 + ni * 16 + lr;
        G[row * 128 + (c ^ (((row >> 2) & 3) << 4))] = f2b(acc[mi][ni][r]);
      }
  __syncthreads();

  const int out = colBase >> 10;
  unsigned short* Co = (out == 0) ? Cq : (out == 1) ? Ck : Cv;
  const int colLocal = colBase & 1023;
#pragma unroll
  for (int it = 0; it < 16; ++it) {
    const int ch  = it * 128 + wc * 64 + lane;   // 2048 chunks: 128 rows x 16
    const int row = ch >> 4, cc = ch & 15;
    const u32x4 v = *(const u32x4*)(G + row * 128 + ((cc * 8) ^ (((row >> 2) & 3) << 4)));
    *(u32x4*)(Co + (rowBase + wr * 128 + row) * 1024 + colLocal + cc * 8) = v;
  }
}

// ---------------------------------------------------------------------------
// Proj GEMM (fp32 out) -- round-4 kernel kept EXACTLY as the control arm.
// 256x128 tile, BK=32, 512 threads (8 waves as 4x2, each owning 64x64).
// ---------------------------------------------------------------------------
template <typename OutT>
__global__ __launch_bounds__(512, 4) void gemm_bt(
    const unsigned short* __restrict__ A,
    const unsigned short* __restrict__ W,
    const float* __restrict__ bias,
    OutT* __restrict__ C,
    int M, int N, int K)
{
  __shared__ __attribute__((aligned(16))) unsigned short Sm[36864];

  const int tid  = threadIdx.x;
  const int lane = tid & 63;
  const int w    = tid >> 6;
  const int wr64 = (w >> 1) * 64;
  const int wc64 = (w & 1) * 64;
  const int lr   = lane & 15;
  const int lg   = lane >> 4;
  const int wofs = w * 512;

  const int nwg     = gridDim.x;
  const int bx      = blockIdx.x;
  const int logical = (bx & 7) * (nwg >> 3) + (bx >> 3);
  const int colsN   = N >> 7;
  const int tileM   = logical / colsN;
  const int tileN   = logical - tileM * colsN;
  const size_t rowBase = (size_t)tileM * 256;
  const int    colBase = tileN * 128;

  const int sRow   = tid >> 2;
  const int sChunk = (tid & 3) ^ ((tid >> 3) & 3);
  const unsigned short* Ag0 = A + (rowBase + sRow) * (size_t)K + sChunk * 8;
  const unsigned short* Ag1 = Ag0 + (size_t)128 * K;
  const unsigned short* Wg0 = W + ((size_t)colBase + sRow) * K + sChunk * 8;

  f32x4 acc[4][4] = {};
  const int nt = K >> 5;

#pragma unroll
  for (int p = 0; p < 2; ++p) {
    const size_t ke = (size_t)p * 32;
    gload_lds16(Ag0 + ke, Sm + p * 8192 + wofs);
    gload_lds16(Ag1 + ke, Sm + p * 8192 + 4096 + wofs);
    gload_lds16(Wg0 + ke, Sm + 24576 + p * 4096 + wofs);
  }

#define GITER(T, VM, STG)                                                     \
  do {                                                                        \
    asm volatile("s_waitcnt vmcnt(" VM ")" ::: "memory");                     \
    __builtin_amdgcn_s_barrier();                                             \
    __builtin_amdgcn_sched_barrier(0);                                        \
    if (STG) {                                                                \
      const int nb = ((T) + 2) % 3;                                           \
      const size_t ke = (size_t)((T) + 2) * 32;                               \
      gload_lds16(Ag0 + ke, Sm + nb * 8192 + wofs);                           \
      gload_lds16(Ag1 + ke, Sm + nb * 8192 + 4096 + wofs);                    \
      gload_lds16(Wg0 + ke, Sm + 24576 + nb * 4096 + wofs);                   \
    }                                                                         \
    const unsigned short* asb = Sm + ((T) % 3) * 8192;                        \
    const unsigned short* bsb = Sm + 24576 + ((T) % 3) * 4096;                \
    bf16x8 af[4], bfv[4];                                                     \
    _Pragma("unroll")                                                         \
    for (int mi = 0; mi < 4; ++mi) {                                          \
      const int row = wr64 + mi * 16 + lr;                                    \
      af[mi] = *(const bf16x8*)(asb + row * 32 + (lg ^ ((row >> 1) & 3)) * 8);\
    }                                                                         \
    _Pragma("unroll")                                                         \
    for (int ni = 0; ni < 4; ++ni) {                                          \
      const int row = wc64 + ni * 16 + lr;                                    \
      bfv[ni] = *(const bf16x8*)(bsb + row * 32 + (lg ^ ((row >> 1) & 3)) * 8);\
    }                                                                         \
    _Pragma("unroll")                                                         \
    for (int mi = 0; mi < 4; ++mi)                                            \
      _Pragma("unroll")                                                       \
      for (int ni = 0; ni < 4; ++ni)                                          \
        acc[mi][ni] = MFMA16(af[mi], bfv[ni], acc[mi][ni]);                   \
  } while (0)

  for (int t = 0; t < nt - 2; ++t) GITER(t, "3", true);
  GITER(nt - 2, "3", false);
  GITER(nt - 1, "0", false);
#undef GITER

  __syncthreads();

  float bv[4];
#pragma unroll
  for (int ni = 0; ni < 4; ++ni)
    bv[ni] = bias ? bias[colBase + wc64 + ni * 16 + lr] : 0.0f;

  const size_t R0 = rowBase + wr64;
  const int    C0 = colBase + wc64;

#pragma unroll
  for (int batch = 0; batch < 2; ++batch) {
    if constexpr (std::is_same_v<OutT, float>) {
      float* reg = (float*)(void*)Sm + w * 2048;
#pragma unroll
      for (int mi2 = 0; mi2 < 2; ++mi2) {
        const int mi = batch * 2 + mi2;
#pragma unroll
        for (int ni = 0; ni < 4; ++ni)
#pragma unroll
          for (int r = 0; r < 4; ++r) {
            const int row = mi2 * 16 + lg * 4 + r;
            reg[row * 64 + ((ni * 16 + lr) ^ (((row >> 2) & 3) << 4))] =
                acc[mi][ni][r] + bv[ni];
          }
      }
      asm volatile("s_waitcnt lgkmcnt(0)" ::: "memory");
      __builtin_amdgcn_sched_barrier(0);
#pragma unroll
      for (int it = 0; it < 8; ++it) {
        const int ch  = it * 64 + lane;
        const int row = ch >> 4, cc = ch & 15;
        const float4 v = *(const float4*)(reg + row * 64 + ((cc * 4) ^ (((row >> 2) & 3) << 4)));
        *(float4*)((float*)C + (R0 + batch * 32 + row) * (size_t)N + C0 + cc * 4) = v;
      }
    } else {
      unsigned short* reg = Sm + w * 2048;
#pragma unroll
      for (int mi2 = 0; mi2 < 2; ++mi2) {
        const int mi = batch * 2 + mi2;
#pragma unroll
        for (int ni = 0; ni < 4; ++ni)
#pragma unroll
          for (int r = 0; r < 4; ++r)
            reg[(mi2 * 16 + lg * 4 + r) * 64 + ni * 16 + lr] =
                f2b(acc[mi][ni][r] + bv[ni]);
      }
      asm volatile("s_waitcnt lgkmcnt(0)" ::: "memory");
      __builtin_amdgcn_sched_barrier(0);
#pragma unroll
      for (int it = 0; it < 4; ++it) {
        const int ch  = it * 64 + lane;
        const int row = ch >> 3, cc = ch & 7;
        const u32x4 v = *(const u32x4*)(reg + row * 64 + cc * 8);
        *(u32x4*)((unsigned short*)C + (R0 + batch * 32 + row) * (size_t)N + C0 + cc * 8) = v;
      }
    }
  }
}

// ---------------------------------------------------------------------------
// Attention pass 1 (yz half): block = (i,b,a,h). 64 queries j, 64 keys k
// (same a, second spatial axis). Writes unnormalized O1 (bf16) + m1,l1 (fp32).
// ---------------------------------------------------------------------------
__global__ __launch_bounds__(256) void attn_yz(
    const unsigned short* __restrict__ Q,
    const unsigned short* __restrict__ Kx,
    const unsigned short* __restrict__ Vx,
    unsigned short* __restrict__ O1,
    float* __restrict__ m1s, float* __restrict__ l1s)
{
  __shared__ __attribute__((aligned(16))) unsigned short Qs[4096], Ks[4096], Vs[4096], Ps[4096];

  const int bid = blockIdx.x;
  const int h = bid & 15;
  const int a = (bid >> 4) & 63;
  const int b = (bid >> 10) & 7;
  const int i = bid >> 13;
  const int i1 = (i + 1) % 3;

  const size_t qoff = ((size_t)((b * 3 + i) * 4096 + a * 64)) * 1024 + h * 64;
  const size_t koff = ((size_t)((b * 3 + i1) * 4096 + a * 64)) * 1024 + h * 64;

  const int tid = threadIdx.x;
#pragma unroll
  for (int it = 0; it < 2; ++it) {
    const int idx = it * 2048 + tid * 8;
    const int row = idx >> 6, col = idx & 63;
    const int d = swz(row, col);
    *(bf16x8*)&Qs[d] = *(const bf16x8*)(Q + qoff + (size_t)row * 1024 + col);
    *(bf16x8*)&Ks[d] = *(const bf16x8*)(Kx + koff + (size_t)row * 1024 + col);
    *(bf16x8*)&Vs[d] = *(const bf16x8*)(Vx + koff + (size_t)row * 1024 + col);
  }
  __syncthreads();

  const int lane = tid & 63;
  const int w  = tid >> 6;
  const int lr = lane & 15;
  const int lg = lane >> 4;

  f32x4 sa[4] = {};
  {
    const bf16x8 aq0 = *(const bf16x8*)&Qs[swz(w * 16 + lr, lg * 8)];
    const bf16x8 aq1 = *(const bf16x8*)&Qs[swz(w * 16 + lr, 32 + lg * 8)];
#pragma unroll
    for (int nf = 0; nf < 4; ++nf) {
      const bf16x8 bk0 = *(const bf16x8*)&Ks[swz(nf * 16 + lr, lg * 8)];
      const bf16x8 bk1 = *(const bf16x8*)&Ks[swz(nf * 16 + lr, 32 + lg * 8)];
      sa[nf] = MFMA16(aq0, bk0, sa[nf]);
      sa[nf] = MFMA16(aq1, bk1, sa[nf]);
    }
  }

  const float scale = 0.125f;
  float m[4], ls[4];
#pragma unroll
  for (int r = 0; r < 4; ++r) {
#pragma unroll
    for (int nf = 0; nf < 4; ++nf) sa[nf][r] *= scale;
    float v = fmaxf(fmaxf(sa[0][r], sa[1][r]), fmaxf(sa[2][r], sa[3][r]));
    v = fmaxf(v, __shfl_xor(v, 1));
    v = fmaxf(v, __shfl_xor(v, 2));
    v = fmaxf(v, __shfl_xor(v, 4));
    v = fmaxf(v, __shfl_xor(v, 8));
    m[r] = v;
    float s = 0.0f;
#pragma unroll
    for (int nf = 0; nf < 4; ++nf) { const float p = __expf(sa[nf][r] - v); sa[nf][r] = p; s += p; }
    s += __shfl_xor(s, 1);
    s += __shfl_xor(s, 2);
    s += __shfl_xor(s, 4);
    s += __shfl_xor(s, 8);
    ls[r] = s;
  }

#pragma unroll
  for (int nf = 0; nf < 4; ++nf)
#pragma unroll
    for (int r = 0; r < 4; ++r)
      Ps[swz(w * 16 + lg * 4 + r, nf * 16 + lr)] = f2b(sa[nf][r]);

  if (lr == 0) {
    const size_t sb = ((size_t)(i * 8 + b) * 16 + h) * 4096 + a * 64 + w * 16 + lg * 4;
#pragma unroll
    for (int r = 0; r < 4; ++r) { m1s[sb + r] = m[r]; l1s[sb + r] = ls[r]; }
  }
  __syncthreads();

  f32x4 oa[4] = {};
#pragma unroll
  for (int ks = 0; ks < 2; ++ks) {
    const bf16x8 ap = *(const bf16x8*)&Ps[swz(w * 16 + lr, ks * 32 + lg * 8)];
#pragma unroll
    for (int df = 0; df < 4; ++df) {
      bf16x8 bv;
#pragma unroll
      for (int e = 0; e < 8; ++e)
        bv[e] = (short)Vs[swz(ks * 32 + lg * 8 + e, df * 16 + lr)];
      oa[df] = MFMA16(ap, bv, oa[df]);
    }
  }

  const size_t ob = ((size_t)(i * 8 + b) * 4096 + a * 64) * 1024 + h * 64;
#pragma unroll
  for (int df = 0; df < 4; ++df)
#pragma unroll
    for (int r = 0; r < 4; ++r)
      O1[ob + (size_t)(w * 16 + lg * 4 + r) * 1024 + df * 16 + lr] = f2b(oa[df][r]);
}

// ---------------------------------------------------------------------------
// Attention pass 2 (zx half) + online-softmax combine in place in O1.
// ---------------------------------------------------------------------------
__global__ __launch_bounds__(256) void attn_zx(
    const unsigned short* __restrict__ Q,
    const unsigned short* __restrict__ Kx,
    const unsigned short* __restrict__ Vx,
    unsigned short* __restrict__ O1,
    const float* __restrict__ m1s, const float* __restrict__ l1s)
{
  __shared__ __attribute__((aligned(16))) unsigned short Qs[4096], Ks[4096], Vs[4096], Ps[4096];

  const int bid = blockIdx.x;
  const int j = bid & 63;
  const int h = (bid >> 6) & 15;
  const int b = (bid >> 10) & 7;
  const int i = bid >> 13;
  const int i2 = (i + 2) % 3;

  const size_t qoff = ((size_t)(b * 3 + i) * 4096 + j) * 1024 + h * 64;
  const size_t koff = ((size_t)(b * 3 + i2) * 4096 + j) * 1024 + h * 64;
  const size_t rstride = 65536;

  const int tid = threadIdx.x;
#pragma unroll
  for (int it = 0; it < 2; ++it) {
    const int idx = it * 2048 + tid * 8;
    const int row = idx >> 6, col = idx & 63;
    const int d = swz(row, col);
    *(bf16x8*)&Qs[d] = *(const bf16x8*)(Q + qoff + (size_t)row * rstride + col);
    *(bf16x8*)&Ks[d] = *(const bf16x8*)(Kx + koff + (size_t)row * rstride + col);
    *(bf16x8*)&Vs[d] = *(const bf16x8*)(Vx + koff + (size_t)row * rstride + col);
  }
  __syncthreads();

  const int lane = tid & 63;
  const int w  = tid >> 6;
  const int lr = lane & 15;
  const int lg = lane >> 4;

  f32x4 sa[4] = {};
  {
    const bf16x8 aq0 = *(const bf16x8*)&Qs[swz(w * 16 + lr, lg * 8)];
    const bf16x8 aq1 = *(const bf16x8*)&Qs[swz(w * 16 + lr, 32 + lg * 8)];
#pragma unroll
    for (int nf = 0; nf < 4; ++nf) {
      const bf16x8 bk0 = *(const bf16x8*)&Ks[swz(nf * 16 + lr, lg * 8)];
      const bf16x8 bk1 = *(const bf16x8*)&Ks[swz(nf * 16 + lr, 32 + lg * 8)];
      sa[nf] = MFMA16(aq0, bk0, sa[nf]);
      sa[nf] = MFMA16(aq1, bk1, sa[nf]);
    }
  }

  const float scale = 0.125f;
  float m[4], ls[4];
#pragma unroll
  for (int r = 0; r < 4; ++r) {
#pragma unroll
    for (int nf = 0; nf < 4; ++nf) sa[nf][r] *= scale;
    float v = fmaxf(fmaxf(sa[0][r], sa[1][r]), fmaxf(sa[2][r], sa[3][r]));
    v = fmaxf(v, __shfl_xor(v, 1));
    v = fmaxf(v, __shfl_xor(v, 2));
    v = fmaxf(v, __shfl_xor(v, 4));
    v = fmaxf(v, __shfl_xor(v, 8));
    m[r] = v;
    float s = 0.0f;
#pragma unroll
    for (int nf = 0; nf < 4; ++nf) { const float p = __expf(sa[nf][r] - v); sa[nf][r] = p; s += p; }
    s += __shfl_xor(s, 1);
    s += __shfl_xor(s, 2);
    s += __shfl_xor(s, 4);
    s += __shfl_xor(s, 8);
    ls[r] = s;
  }

  float c1[4], c2[4], rden[4];
  const size_t sb = ((size_t)(i * 8 + b) * 16 + h) * 4096 + j;
#pragma unroll
  for (int r = 0; r < 4; ++r) {
    const int arow = w * 16 + lg * 4 + r;
    const float mm1 = m1s[sb + (size_t)arow * 64];
    const float ll1 = l1s[sb + (size_t)arow * 64];
    const float mm = fmaxf(mm1, m[r]);
    const float e1 = __expf(mm1 - mm);
    const float e2 = __expf(m[r] - mm);
    c1[r] = e1; c2[r] = e2;
    rden[r] = 1.0f / (e1 * ll1 + e2 * ls[r]);
  }

#pragma unroll
  for (int nf = 0; nf < 4; ++nf)
#pragma unroll
    for (int r = 0; r < 4; ++r)
      Ps[swz(w * 16 + lg * 4 + r, nf * 16 + lr)] = f2b(sa[nf][r]);
  __syncthreads();

  f32x4 oa[4] = {};
#pragma unroll
  for (int ks = 0; ks < 2; ++ks) {
    const bf16x8 ap = *(const bf16x8*)&Ps[swz(w * 16 + lr, ks * 32 + lg * 8)];
#pragma unroll
    for (int df = 0; df < 4; ++df) {
      bf16x8 bv;
#pragma unroll
      for (int e = 0; e < 8; ++e)
        bv[e] = (short)Vs[swz(ks * 32 + lg * 8 + e, df * 16 + lr)];
      oa[df] = MFMA16(ap, bv, oa[df]);
    }
  }

  const size_t ob = ((size_t)(i * 8 + b) * 4096 + j) * 1024 + h * 64;
#pragma unroll
  for (int df = 0; df < 4; ++df)
#pragma unroll
    for (int r = 0; r < 4; ++r) {
      const size_t addr = ob + (size_t)(w * 16 + lg * 4 + r) * rstride + df * 16 + lr;
      const float o1v = b2f(O1[addr]);
      O1[addr] = f2b((c1[r] * o1v + c2[r] * oa[df][r]) * rden[r]);
    }
}

// ---------------------------------------------------------------------------
extern "C" void kernel_launch(void* const* d_in, const int* in_sizes, int n_in,
                              void* d_out, int out_size, void* d_ws, size_t ws_size,
                              hipStream_t stream)
{
  const float* x  = (const float*)d_in[0];
  const float* wq = (const float*)d_in[1];
  const float* wk = (const float*)d_in[2];
  const float* wv = (const float*)d_in[3];
  const float* wp = (const float*)d_in[4];
  const float* bp = (const float*)d_in[5];

  const int M = 98304, N = 1024, K = 1024;
  const size_t SLAB = 201326592ull;   // 98304*1024*2 bytes (bf16 slab)
  const size_t STAT = 6291456ull;     // 3*8*16*4096 floats

  char* ws = (char*)d_ws;
  unsigned short* xb  = (unsigned short*)(ws);            // converted x; reused as O1 after QKV
  unsigned short* Kb  = (unsigned short*)(ws + SLAB);
  unsigned short* Vb  = (unsigned short*)(ws + 2 * SLAB);
  float* m1s          = (float*)(ws + 3 * SLAB);
  float* l1s          = (float*)(ws + 3 * SLAB + STAT);
  unsigned short* wqb = (unsigned short*)(ws + 3 * SLAB + 2 * STAT);  // [wq;wk;wv;wp] contiguous
  unsigned short* wpb = wqb + 3145728;
  unsigned short* Qb  = (unsigned short*)d_out;  // bf16 Q scratch in fp32 d_out; dead before final write
  unsigned short* O1  = xb;                      // x slab dead after the fused QKV GEMM

  dim3 blk(256);
  cvt_f32_bf16<<<dim3(4096), blk, 0, stream>>>(x, xb, (long long)M * 1024);
  cvt4_w<<<dim3(2048), blk, 0, stream>>>(wq, wk, wv, wp, wqb);

  // Fused QKV: A @ [wq;wk;wv]^T -> Qb,Kb,Vb.  grid = 8 XCD * 384 tileM * 3
  gemm_qkv<<<dim3((M / 256) * (3072 / 128)), dim3(256), 0, stream>>>(
      xb, wqb, Qb, Kb, Vb, M, 3072, K);

  attn_yz<<<dim3(24576), blk, 0, stream>>>(Qb, Kb, Vb, O1, m1s, l1s);
  attn_zx<<<dim3(24576), blk, 0, stream>>>(Qb, Kb, Vb, O1, m1s, l1s);

  // Proj (control arm: round-4 kernel unchanged). grid = 384*8 = 3072
  gemm_bt<float><<<dim3((M / 256) * (N / 128)), dim3(512), 0, stream>>>(
      O1, wpb, bp, (float*)d_out, M, N, K);
}